// Round 4
// baseline (3512.555 us; speedup 1.0000x reference)
//
#include <hip/hip_runtime.h>
#include <hip/hip_bf16.h>
#include <math.h>

#define B_ 4
#define N_ 2048
#define D_ 512
#define H_ 8
#define HD_ 64
#define KW_ 9
#define P_ 8
#define E_ 4
#define HID_ 2048
#define TOK_ (B_*N_)   // 8192

static __device__ __forceinline__ float wave_sum(float v){
#pragma unroll
  for(int off=32; off>0; off>>=1) v += __shfl_xor(v, off);
  return v;
}

static __device__ __forceinline__ float gelu_exact(float v){
  return 0.5f * v * (1.f + erff(v * 0.70710678118654752440f));
}

// ---------------- LayerNorm (one block per row of 512) ----------------
__global__ __launch_bounds__(256) void ln_kernel(const float* __restrict__ in,
    const float* __restrict__ g, const float* __restrict__ b,
    float* __restrict__ out, float eps)
{
  int r = blockIdx.x;
  int tid = threadIdx.x;
  const float* rp = in + (size_t)r * D_;
  float2 v = *(const float2*)(rp + tid*2);
  float s = v.x + v.y;
  float q = v.x*v.x + v.y*v.y;
  s = wave_sum(s); q = wave_sum(q);
  __shared__ float ss[4], qq[4];
  int wid = tid >> 6, lane = tid & 63;
  if(lane==0){ ss[wid]=s; qq[wid]=q; }
  __syncthreads();
  float S = ss[0]+ss[1]+ss[2]+ss[3];
  float Q = qq[0]+qq[1]+qq[2]+qq[3];
  float mean = S * (1.f/D_);
  float var = Q * (1.f/D_) - mean*mean;
  float rstd = rsqrtf(var + eps);
  int d = tid*2;
  float2 o;
  o.x = (v.x-mean)*rstd*g[d]   + b[d];
  o.y = (v.y-mean)*rstd*g[d+1] + b[d+1];
  *(float2*)(out + (size_t)r*D_ + d) = o;
}

// ---------------- f32 GEMM: C = A(MxK) @ W(KxN) + bias, epilogues ----------------
// As stored TRANSPOSED [k][m] so both operand reads are ds_read_b128.
#define EPI_PLAIN 0
#define EPI_GELU  1
#define EPI_RESID 2
#define EPI_ACC   3

template<int EPI>
__global__ __launch_bounds__(256) void gemm_f32(
    const float* __restrict__ A, const float* __restrict__ W,
    const float* __restrict__ bias, float* __restrict__ out,
    int M, int Kd, int Nw,
    const float* __restrict__ resid,
    const float* __restrict__ gate, int gstride)
{
  __shared__ __align__(16) float As[16][128];  // [k][m] transposed
  __shared__ __align__(16) float Bs[16][128];  // [k][n]
  int tid = threadIdx.x;
  int tx = tid & 15, ty = tid >> 4;
  int row0 = blockIdx.y * 128, col0 = blockIdx.x * 128;
  float acc[8][8];
#pragma unroll
  for(int i=0;i<8;++i)
#pragma unroll
    for(int j=0;j<8;++j) acc[i][j]=0.f;

  for(int k0=0; k0<Kd; k0+=16){
#pragma unroll
    for(int i=0;i<2;++i){
      int f4 = tid*2+i;
      int r  = f4 >> 2;           // m index 0..127
      int kc = (f4 & 3) << 2;     // k index 0,4,8,12
      int gr = row0 + r;
      float4 v = make_float4(0.f,0.f,0.f,0.f);
      if (gr < M) v = *(const float4*)(A + (size_t)gr*Kd + k0 + kc);
      As[kc+0][r]=v.x; As[kc+1][r]=v.y; As[kc+2][r]=v.z; As[kc+3][r]=v.w;
    }
#pragma unroll
    for(int i=0;i<2;++i){
      int f4 = tid*2+i;
      int kr = f4 >> 5;
      int c  = (f4 & 31) << 2;
      *(float4*)&Bs[kr][c] = *(const float4*)(W + (size_t)(k0+kr)*Nw + col0 + c);
    }
    __syncthreads();
#pragma unroll
    for(int kk=0;kk<16;++kk){
      float a[8], b[8];
      float4 a0 = *(const float4*)&As[kk][ty*8];
      float4 a1 = *(const float4*)&As[kk][ty*8+4];
      a[0]=a0.x;a[1]=a0.y;a[2]=a0.z;a[3]=a0.w;
      a[4]=a1.x;a[5]=a1.y;a[6]=a1.z;a[7]=a1.w;
      float4 b0 = *(const float4*)&Bs[kk][tx*8];
      float4 b1 = *(const float4*)&Bs[kk][tx*8+4];
      b[0]=b0.x;b[1]=b0.y;b[2]=b0.z;b[3]=b0.w;
      b[4]=b1.x;b[5]=b1.y;b[6]=b1.z;b[7]=b1.w;
#pragma unroll
      for(int i=0;i<8;++i)
#pragma unroll
        for(int j=0;j<8;++j)
          acc[i][j] = fmaf(a[i], b[j], acc[i][j]);
    }
    __syncthreads();
  }

#pragma unroll
  for(int i=0;i<8;++i){
    int gr = row0 + ty*8 + i;
    if (gr >= M) continue;
    size_t rb = (size_t)gr * Nw;
    float gv = 1.f;
    if (EPI == EPI_ACC && gate != nullptr) gv = gate[(size_t)gr * gstride];
#pragma unroll
    for(int j=0;j<8;++j){
      int gc = col0 + tx*8 + j;
      float v = acc[i][j] + bias[gc];
      if (EPI == EPI_GELU)  v = gelu_exact(v);
      if (EPI == EPI_RESID) v += resid[rb + gc];
      if (EPI == EPI_ACC) out[rb+gc] += gv * v;
      else                out[rb+gc] = v;
    }
  }
}

// ---------------- q post: l2 -> scale(softplus(temp)*ln16) -> rope (in place) -----
__global__ __launch_bounds__(256) void qs_post_kernel(float* __restrict__ q,
                                                      const float* __restrict__ temp)
{
  int tid = threadIdx.x;
  int gid = blockIdx.x*4 + (tid>>6);      // (b*N+n)*H + h
  int dd  = tid & 63;
  int h = gid % H_;
  int n = (gid / H_) % N_;
  int b = gid / (H_*N_);
  size_t idx = ((size_t)(b*N_+n))*D_ + h*HD_ + dd;
  float v = q[idx];
  float ss = wave_sum(v*v);
  v = v / fmaxf(sqrtf(ss), 1e-12f);
  float t = temp[h];
  float sp = log1pf(expf(t));             // softplus
  v *= sp * 2.77258872223978124f;         // ln(K-1+P) = ln(16)
  float partner = __shfl_xor(v, 32);
  int i = dd & 31;
  float inv = 1.f / powf(10000.f, (float)i * (1.f/32.f));
  float ang = (float)n * inv;
  float s, c; sincosf(ang, &s, &c);
  q[idx] = (dd < 32) ? fmaf(v, c, -partner*s) : fmaf(partner, s, v*c);
}

// ---------------- k post: rope -> l2, kv(B,N,2D) -> kln(B,N,D head layout) -------
__global__ __launch_bounds__(256) void k_post_kernel(const float* __restrict__ kvb,
                                                     float* __restrict__ kln)
{
  int tid = threadIdx.x;
  int gid = blockIdx.x*4 + (tid>>6);
  int dd  = tid & 63;
  int h = gid % H_;
  int n = (gid / H_) % N_;
  int b = gid / (H_*N_);
  float v = kvb[((size_t)(b*N_+n))*(2*D_) + h*HD_ + dd];
  float partner = __shfl_xor(v, 32);
  int i = dd & 31;
  float inv = 1.f / powf(10000.f, (float)i * (1.f/32.f));
  float ang = (float)n * inv;
  float s, c; sincosf(ang, &s, &c);
  float r = (dd < 32) ? fmaf(v, c, -partner*s) : fmaf(partner, s, v*c);
  float ss = wave_sum(r*r);
  r = r / fmaxf(sqrtf(ss), 1e-12f);
  kln[((size_t)(b*N_+n))*D_ + h*HD_ + dd] = r;
}

// ---------------- pooled path: mean over 256 tokens + LN(eps 1e-5) ---------------
__global__ __launch_bounds__(256) void pool_ln_kernel(const float* __restrict__ src,
    const float* __restrict__ g, const float* __restrict__ b, float* __restrict__ xp)
{
  int bp = blockIdx.x;          // b*P+p
  int bb = bp / P_, p = bp % P_;
  int tid = threadIdx.x;
  const float* base = src + ((size_t)(bb*N_ + p*(N_/P_)))*D_;
  float a0=0.f, a1=0.f;
  for(int i=0;i<N_/P_;++i){
    a0 += base[(size_t)i*D_ + tid];
    a1 += base[(size_t)i*D_ + tid + 256];
  }
  a0 *= (1.f/(N_/P_)); a1 *= (1.f/(N_/P_));
  float s = a0+a1, q = a0*a0+a1*a1;
  s = wave_sum(s); q = wave_sum(q);
  __shared__ float ss[4], qq[4];
  int wid = tid>>6, lane = tid&63;
  if(lane==0){ ss[wid]=s; qq[wid]=q; }
  __syncthreads();
  float S = ss[0]+ss[1]+ss[2]+ss[3];
  float Q = qq[0]+qq[1]+qq[2]+qq[3];
  float mean = S*(1.f/D_);
  float var  = Q*(1.f/D_) - mean*mean;
  float rstd = rsqrtf(var + 1e-5f);
  xp[(size_t)bp*D_ + tid]       = (a0-mean)*rstd*g[tid]     + b[tid];
  xp[(size_t)bp*D_ + tid + 256] = (a1-mean)*rstd*g[tid+256] + b[tid+256];
}

// ---------------- kP rope (pos = p), kvp(B*P,2D) -> kpb(B*P,D) -------------------
__global__ __launch_bounds__(512) void kp_rope_kernel(const float* __restrict__ kvp,
                                                      float* __restrict__ kpb)
{
  int bp = blockIdx.x;          // b*P+p
  int d  = threadIdx.x;         // 0..511 (8 waves, one head each)
  int dd = d & 63;
  int p  = bp % P_;
  float v = kvp[(size_t)bp*(2*D_) + d];
  float partner = __shfl_xor(v, 32);
  int i = dd & 31;
  float inv = 1.f / powf(10000.f, (float)i * (1.f/32.f));
  float ang = (float)p * inv;
  float s, c; sincosf(ang, &s, &c);
  kpb[(size_t)bp*D_ + d] = (dd < 32) ? fmaf(v, c, -partner*s) : fmaf(partner, s, v*c);
}

// ---------------- attention: 17 logits -> softmax -> weighted V ------------------
__global__ __launch_bounds__(256) void attn_kernel(
    const float* __restrict__ qs, const float* __restrict__ kln,
    const float* __restrict__ kvb, const float* __restrict__ kpb,
    const float* __restrict__ kvp, float* __restrict__ outb)
{
  int tid = threadIdx.x;
  int gid = blockIdx.x*4 + (tid>>6);   // (b*N+n)*H + h
  int dd  = tid & 63;
  int h = gid % H_;
  int n = (gid / H_) % N_;
  int b = gid / (H_*N_);
  size_t tok = (size_t)(b*N_+n);
  float qv = qs[tok*D_ + h*HD_ + dd];
  float l[KW_+P_];
#pragma unroll
  for(int j=0;j<KW_;++j){
    int np  = n - KW_/2 + j;
    int npc = min(max(np,0), N_-1);
    float kd = kln[((size_t)(b*N_+npc))*D_ + h*HD_ + dd];
    float sdot = wave_sum(qv*kd);
    l[j] = (np>=0 && np<N_) ? sdot : -3.0e38f;
  }
#pragma unroll
  for(int p=0;p<P_;++p){
    float kd = kpb[((size_t)(b*P_+p))*D_ + h*HD_ + dd];
    l[KW_+p] = wave_sum(qv*kd);
  }
  float m = l[0];
#pragma unroll
  for(int j=1;j<KW_+P_;++j) m = fmaxf(m, l[j]);
  float a[KW_+P_]; float sum = 0.f;
#pragma unroll
  for(int j=0;j<KW_+P_;++j){ a[j] = expf(l[j]-m); sum += a[j]; }
  float inv = 1.f / sum;
  float o = 0.f;
#pragma unroll
  for(int j=0;j<KW_;++j){
    int npc = min(max(n - KW_/2 + j, 0), N_-1);
    o = fmaf(a[j], kvb[((size_t)(b*N_+npc))*(2*D_) + D_ + h*HD_ + dd], o);
  }
#pragma unroll
  for(int p=0;p<P_;++p){
    o = fmaf(a[KW_+p], kvp[((size_t)(b*P_+p))*(2*D_) + D_ + h*HD_ + dd], o);
  }
  outb[tok*D_ + h*HD_ + dd] = o * inv;
}

// ---------------- router + gate stats --------------------------------------------
__global__ void zero_stats_kernel(float* stats){
  if(threadIdx.x < 16) stats[threadIdx.x] = 0.f;
}

__global__ __launch_bounds__(256) void router_kernel(const float* __restrict__ xn2,
    const float* __restrict__ rw, const float* __restrict__ rb,
    float* __restrict__ gates, float* __restrict__ stats)
{
  int tid = threadIdx.x;
  int wid = tid>>6, lane = tid&63;
  int t = blockIdx.x*4 + wid;
  const float* xr = xn2 + (size_t)t*D_;
  float a0=0.f,a1=0.f,a2=0.f,a3=0.f;
  for(int k=lane;k<D_;k+=64){
    float xv = xr[k];
    float4 w = *(const float4*)(rw + (size_t)k*E_);
    a0 = fmaf(xv,w.x,a0); a1 = fmaf(xv,w.y,a1);
    a2 = fmaf(xv,w.z,a2); a3 = fmaf(xv,w.w,a3);
  }
  a0=wave_sum(a0); a1=wave_sum(a1); a2=wave_sum(a2); a3=wave_sum(a3);
  __shared__ float sg[4][E_], sc[4][E_];
  if(lane==0){
    float lg[E_] = {a0+rb[0], a1+rb[1], a2+rb[2], a3+rb[3]};
    float m = fmaxf(fmaxf(lg[0],lg[1]), fmaxf(lg[2],lg[3]));
    float e[E_]; float sum=0.f;
#pragma unroll
    for(int k=0;k<E_;++k){ e[k]=expf(lg[k]-m); sum+=e[k]; }
    float inv = 1.f/sum;
    int am = 0; float bv = lg[0];
#pragma unroll
    for(int k=1;k<E_;++k) if(lg[k] > bv){ bv = lg[k]; am = k; }
#pragma unroll
    for(int k=0;k<E_;++k){
      float gk = e[k]*inv;
      gates[(size_t)t*E_ + k] = gk;
      sg[wid][k] = gk;
      sc[wid][k] = (k==am) ? 1.f : 0.f;
    }
  }
  __syncthreads();
  if(tid < E_){
    atomicAdd(stats + tid,      sc[0][tid]+sc[1][tid]+sc[2][tid]+sc[3][tid]);
    atomicAdd(stats + E_ + tid, sg[0][tid]+sg[1][tid]+sg[2][tid]+sg[3][tid]);
  }
}

__global__ void aux_kernel(const float* __restrict__ stats, float* __restrict__ outp){
  float acc = 0.f;
  const float inv = 1.f / (float)TOK_;
#pragma unroll
  for(int e=0;e<E_;++e) acc += (stats[e]*inv) * (stats[E_+e]*inv);
  *outp = 0.01f * (float)E_ * acc;
}

// =================================================================================
extern "C" void kernel_launch(void* const* d_in, const int* in_sizes, int n_in,
                              void* d_out, int out_size, void* d_ws, size_t ws_size,
                              hipStream_t stream)
{
  const float* x      = (const float*)d_in[0];
  const float* temp   = (const float*)d_in[1];
  const float* q_w    = (const float*)d_in[2];
  const float* q_b    = (const float*)d_in[3];
  const float* kv_w   = (const float*)d_in[4];
  const float* kv_b   = (const float*)d_in[5];
  const float* proj_w = (const float*)d_in[6];
  const float* proj_b = (const float*)d_in[7];
  const float* n1g    = (const float*)d_in[8];
  const float* n1b    = (const float*)d_in[9];
  const float* n2g    = (const float*)d_in[10];
  const float* n2b    = (const float*)d_in[11];
  const float* sr_w   = (const float*)d_in[12];
  const float* sr_b   = (const float*)d_in[13];
  const float* npg    = (const float*)d_in[14];
  const float* npb    = (const float*)d_in[15];
  const float* rw     = (const float*)d_in[16];
  const float* rb     = (const float*)d_in[17];
  const float* ew1    = (const float*)d_in[18];
  const float* eb1    = (const float*)d_in[19];
  const float* ew2    = (const float*)d_in[20];
  const float* eb2    = (const float*)d_in[21];
  const float* sw1    = (const float*)d_in[22];
  const float* sb1    = (const float*)d_in[23];
  const float* sw2    = (const float*)d_in[24];
  const float* sb2    = (const float*)d_in[25];

  float* out = (float*)d_out;
  float* ws  = (float*)d_ws;
  const size_t S = (size_t)TOK_ * D_;          // 4,194,304 floats
  float* xn    = ws;            // xn; later attn_out; later MoE hidden (4S @ ws)
  float* qsb   = ws + S;        // q -> qs
  float* kvb   = ws + 2*S;      // kv (2S)
  float* kln   = ws + 4*S;      // processed local K
  float* xn2   = ws + 5*S;      // gelu(sr) pooling source, later xn2
  float* xp    = ws + 6*S;
  float* kvp   = xp  + (size_t)B_*P_*D_;
  float* kpb   = kvp + (size_t)B_*P_*2*D_;
  float* gates = kpb + (size_t)B_*P_*D_;
  float* stats = gates + (size_t)TOK_*E_;

  // 1. xn = LN1(x)
  ln_kernel<<<dim3(TOK_), 256, 0, stream>>>(x, n1g, n1b, xn, 1e-6f);
  // 2. q = xn @ q_w + q_b
  gemm_f32<EPI_PLAIN><<<dim3(4,64), 256, 0, stream>>>(xn, q_w, q_b, qsb, TOK_, D_, D_, nullptr, nullptr, 0);
  // 3. kv = xn @ kv_w + kv_b
  gemm_f32<EPI_PLAIN><<<dim3(8,64), 256, 0, stream>>>(xn, kv_w, kv_b, kvb, TOK_, D_, 2*D_, nullptr, nullptr, 0);
  // 4. gelu(xn @ sr_w + sr_b) -> xn2 buffer (pooling source)
  gemm_f32<EPI_GELU><<<dim3(4,64), 256, 0, stream>>>(xn, sr_w, sr_b, xn2, TOK_, D_, D_, nullptr, nullptr, 0);
  // 5. xp = LN(mean-pool)
  pool_ln_kernel<<<dim3(B_*P_), 256, 0, stream>>>(xn2, npg, npb, xp);
  // 6. kvp = xp @ kv_w + kv_b
  gemm_f32<EPI_PLAIN><<<dim3(8,1), 256, 0, stream>>>(xp, kv_w, kv_b, kvp, B_*P_, D_, 2*D_, nullptr, nullptr, 0);
  // 7. kP = rope(kvp[:, :D], pos=p)
  kp_rope_kernel<<<dim3(B_*P_), 512, 0, stream>>>(kvp, kpb);
  // 8. qs = rope(l2(q)*softplus(temp)*ln16)
  qs_post_kernel<<<dim3(B_*N_*H_/4), 256, 0, stream>>>(qsb, temp);
  // 9. kln = l2(rope(kL))
  k_post_kernel<<<dim3(B_*N_*H_/4), 256, 0, stream>>>(kvb, kln);
  // 10. attention -> xn (reused as attn_out)
  attn_kernel<<<dim3(B_*H_*N_/4), 256, 0, stream>>>(qsb, kln, kvb, kpb, kvp, xn);
  // 11. out = x + attn_out @ proj_w + proj_b
  gemm_f32<EPI_RESID><<<dim3(4,64), 256, 0, stream>>>(xn, proj_w, proj_b, out, TOK_, D_, D_, x, nullptr, 0);
  // 12. xn2 = LN2(out)
  ln_kernel<<<dim3(TOK_), 256, 0, stream>>>(out, n2g, n2b, xn2, 1e-6f);
  // 13-14. router + stats
  zero_stats_kernel<<<dim3(1), 64, 0, stream>>>(stats);
  router_kernel<<<dim3(TOK_/4), 256, 0, stream>>>(xn2, rw, rb, gates, stats);
  // 15. MoE full-TOK: hidden reuses ws[0..4S) (xn/qsb/kvb all dead here).
  float* hid = ws;   // TOK_ x HID_ = 4S floats
  gemm_f32<EPI_GELU><<<dim3(16,64), 256, 0, stream>>>(xn2, sw1, sb1, hid, TOK_, D_, HID_, nullptr, nullptr, 0);
  gemm_f32<EPI_ACC ><<<dim3(4,64),  256, 0, stream>>>(hid, sw2, sb2, out, TOK_, HID_, D_, nullptr, nullptr, 0);
  for(int e=0;e<E_;++e){
    gemm_f32<EPI_GELU><<<dim3(16,64), 256, 0, stream>>>(xn2, ew1 + (size_t)e*D_*HID_, eb1 + (size_t)e*HID_, hid, TOK_, D_, HID_, nullptr, nullptr, 0);
    gemm_f32<EPI_ACC ><<<dim3(4,64),  256, 0, stream>>>(hid, ew2 + (size_t)e*HID_*D_, eb2 + (size_t)e*D_, out, TOK_, HID_, D_, nullptr, gates + e, E_);
  }
  // 16. aux scalar
  aux_kernel<<<dim3(1), 1, 0, stream>>>(stats, out + S);
}

// Round 5
// 1432.183 us; speedup vs baseline: 2.4526x; 2.4526x over previous
//
#include <hip/hip_runtime.h>
#include <hip/hip_bf16.h>
#include <math.h>

#define B_ 4
#define N_ 2048
#define D_ 512
#define H_ 8
#define HD_ 64
#define KW_ 9
#define P_ 8
#define E_ 4
#define HID_ 2048
#define TOK_ (B_*N_)   // 8192

typedef __bf16 bf16x8 __attribute__((ext_vector_type(8)));
typedef float  f32x4  __attribute__((ext_vector_type(4)));

static __device__ __forceinline__ float wave_sum(float v){
#pragma unroll
  for(int off=32; off>0; off>>=1) v += __shfl_xor(v, off);
  return v;
}

static __device__ __forceinline__ float gelu_exact(float v){
  return 0.5f * v * (1.f + erff(v * 0.70710678118654752440f));
}

// split f32 into hi+lo bf16 (3-term MFMA gives ~f32 product precision)
static __device__ __forceinline__ void split2(float v, unsigned short& h, unsigned short& l){
  __bf16 bh = (__bf16)v;
  float r = v - (float)bh;
  __bf16 bl = (__bf16)r;
  h = __builtin_bit_cast(unsigned short, bh);
  l = __builtin_bit_cast(unsigned short, bl);
}
static __device__ __forceinline__ float bf2f(unsigned short u){
  return (float)__builtin_bit_cast(__bf16, u);
}

// ---------------- weight convert: W f32 [K][N] -> Wt hi/lo bf16 [N][K] ----------
__global__ __launch_bounds__(256) void wconv_kernel(const float* __restrict__ W,
    unsigned short* __restrict__ Th, unsigned short* __restrict__ Tl, int K, int N)
{
  size_t ms = (size_t)K*N;
  const float* Wb = W + blockIdx.z*ms;
  unsigned short* Thb = Th + blockIdx.z*ms;
  unsigned short* Tlb = Tl + blockIdx.z*ms;
  __shared__ float tile[64][65];
  int n0 = blockIdx.x*64, k0 = blockIdx.y*64;
  int t = threadIdx.x;
  int c4 = (t&15)*4, r = t>>4;
#pragma unroll
  for(int pass=0; pass<4; ++pass){
    int k = r + pass*16;
    float4 v = *(const float4*)(Wb + (size_t)(k0+k)*N + n0 + c4);
    tile[k][c4]=v.x; tile[k][c4+1]=v.y; tile[k][c4+2]=v.z; tile[k][c4+3]=v.w;
  }
  __syncthreads();
#pragma unroll
  for(int pass=0; pass<4; ++pass){
    int n = r + pass*16;
    unsigned short h0,h1,h2,h3,l0,l1,l2,l3;
    split2(tile[c4+0][n], h0, l0);
    split2(tile[c4+1][n], h1, l1);
    split2(tile[c4+2][n], h2, l2);
    split2(tile[c4+3][n], h3, l3);
    *(ushort4*)(Thb + (size_t)(n0+n)*K + k0 + c4) = make_ushort4(h0,h1,h2,h3);
    *(ushort4*)(Tlb + (size_t)(n0+n)*K + k0 + c4) = make_ushort4(l0,l1,l2,l3);
  }
}

// ---------------- split-bf16 MFMA GEMM: C = (Ah+Al)(Bh+Bl) + bias ----------------
// A [M][K] bf16 planes, Bt [N][K] bf16 planes. Tile 128x128, BK=64, 4 waves.
// LDS XOR swizzle: 16B chunk index ^= (row&7) on both write and read.
#define GEPI_PLAIN     0
#define GEPI_GELU_F32  1
#define GEPI_RESID     2
#define GEPI_ACC       3
#define GEPI_GELU_HILO 4

template<int EPI>
__global__ __launch_bounds__(256,2) void gemm_mfma(
    const unsigned short* __restrict__ Ah, const unsigned short* __restrict__ Al,
    const unsigned short* __restrict__ Bh, const unsigned short* __restrict__ Bl,
    const float* __restrict__ bias,
    float* __restrict__ out, unsigned short* __restrict__ outh, unsigned short* __restrict__ outl,
    int M, int K, int N,
    const float* __restrict__ resid, const float* __restrict__ gate, int gstride)
{
  __shared__ unsigned short lds[4][128][64];   // Ah,Al,Bh,Bl tiles; 64 KB
  int tid = threadIdx.x;
  int lane = tid & 63, w = tid >> 6;
  int wm = w >> 1, wn = w & 1;
  int row0 = blockIdx.y*128, col0 = blockIdx.x*128;
  int r15 = lane & 15, g = lane >> 4;
  f32x4 acc[4][4];
#pragma unroll
  for(int i=0;i<4;++i)
#pragma unroll
    for(int j=0;j<4;++j) acc[i][j] = (f32x4){0.f,0.f,0.f,0.f};

  for(int k0=0; k0<K; k0+=64){
    __syncthreads();
#pragma unroll
    for(int i=0;i<16;++i){
      const int plane = i>>2;                   // compile-time per unrolled i
      int row = (i&3)*32 + (tid>>3);
      int gc  = tid & 7;
      const unsigned short* src;
      if(plane==0)      src = Ah + (size_t)(row0+row)*K + k0 + gc*8;
      else if(plane==1) src = Al + (size_t)(row0+row)*K + k0 + gc*8;
      else if(plane==2) src = Bh + (size_t)(col0+row)*K + k0 + gc*8;
      else              src = Bl + (size_t)(col0+row)*K + k0 + gc*8;
      int4 v = *(const int4*)src;
      int dc = gc ^ (row & 7);
      *(int4*)&lds[plane][row][dc*8] = v;
    }
    __syncthreads();
#pragma unroll
    for(int ks=0; ks<2; ++ks){
      bf16x8 afh[4], afl[4], bfh[4], bfl[4];
#pragma unroll
      for(int mf=0; mf<4; ++mf){
        int row = wm*64 + mf*16 + r15;
        int ch = (ks*4 + g) ^ (row & 7);
        afh[mf] = *(const bf16x8*)&lds[0][row][ch*8];
        afl[mf] = *(const bf16x8*)&lds[1][row][ch*8];
      }
#pragma unroll
      for(int nf=0; nf<4; ++nf){
        int row = wn*64 + nf*16 + r15;
        int ch = (ks*4 + g) ^ (row & 7);
        bfh[nf] = *(const bf16x8*)&lds[2][row][ch*8];
        bfl[nf] = *(const bf16x8*)&lds[3][row][ch*8];
      }
#pragma unroll
      for(int mf=0; mf<4; ++mf)
#pragma unroll
        for(int nf=0; nf<4; ++nf){
          acc[mf][nf] = __builtin_amdgcn_mfma_f32_16x16x32_bf16(afh[mf], bfh[nf], acc[mf][nf], 0,0,0);
          acc[mf][nf] = __builtin_amdgcn_mfma_f32_16x16x32_bf16(afh[mf], bfl[nf], acc[mf][nf], 0,0,0);
          acc[mf][nf] = __builtin_amdgcn_mfma_f32_16x16x32_bf16(afl[mf], bfh[nf], acc[mf][nf], 0,0,0);
        }
    }
  }
  // epilogue: D col = lane&15 (N), row = (lane>>4)*4 + v (M)  [m89-verified layout]
#pragma unroll
  for(int mf=0; mf<4; ++mf){
#pragma unroll
    for(int nf=0; nf<4; ++nf){
      int col = col0 + wn*64 + nf*16 + r15;
      float bv = bias[col];
#pragma unroll
      for(int v=0; v<4; ++v){
        int row = row0 + wm*64 + mf*16 + g*4 + v;
        size_t o = (size_t)row*N + col;
        float val = acc[mf][nf][v] + bv;
        if      (EPI == GEPI_GELU_F32){ out[o] = gelu_exact(val); }
        else if (EPI == GEPI_GELU_HILO){
          float gv = gelu_exact(val);
          unsigned short hh, ll; split2(gv, hh, ll);
          outh[o] = hh; outl[o] = ll;
        }
        else if (EPI == GEPI_RESID){ out[o] = val + resid[o]; }
        else if (EPI == GEPI_ACC){
          float gv = gate ? gate[(size_t)row*gstride] : 1.f;
          out[o] += gv * val;
        }
        else { out[o] = val; }
      }
    }
  }
}

// ---------------- legacy f32 vector GEMM (only for the tiny 32-row kvp GEMM) -----
#define EPI_PLAIN 0
template<int EPI>
__global__ __launch_bounds__(256) void gemm_f32(
    const float* __restrict__ A, const float* __restrict__ W,
    const float* __restrict__ bias, float* __restrict__ out,
    int M, int Kd, int Nw,
    const float* __restrict__ resid,
    const float* __restrict__ gate, int gstride)
{
  __shared__ __align__(16) float As[16][128];
  __shared__ __align__(16) float Bs[16][128];
  int tid = threadIdx.x;
  int tx = tid & 15, ty = tid >> 4;
  int row0 = blockIdx.y * 128, col0 = blockIdx.x * 128;
  float acc[8][8];
#pragma unroll
  for(int i=0;i<8;++i)
#pragma unroll
    for(int j=0;j<8;++j) acc[i][j]=0.f;

  for(int k0=0; k0<Kd; k0+=16){
#pragma unroll
    for(int i=0;i<2;++i){
      int f4 = tid*2+i;
      int r  = f4 >> 2;
      int kc = (f4 & 3) << 2;
      int gr = row0 + r;
      float4 v = make_float4(0.f,0.f,0.f,0.f);
      if (gr < M) v = *(const float4*)(A + (size_t)gr*Kd + k0 + kc);
      As[kc+0][r]=v.x; As[kc+1][r]=v.y; As[kc+2][r]=v.z; As[kc+3][r]=v.w;
    }
#pragma unroll
    for(int i=0;i<2;++i){
      int f4 = tid*2+i;
      int kr = f4 >> 5;
      int c  = (f4 & 31) << 2;
      *(float4*)&Bs[kr][c] = *(const float4*)(W + (size_t)(k0+kr)*Nw + col0 + c);
    }
    __syncthreads();
#pragma unroll
    for(int kk=0;kk<16;++kk){
      float a[8], b[8];
      float4 a0 = *(const float4*)&As[kk][ty*8];
      float4 a1 = *(const float4*)&As[kk][ty*8+4];
      a[0]=a0.x;a[1]=a0.y;a[2]=a0.z;a[3]=a0.w;
      a[4]=a1.x;a[5]=a1.y;a[6]=a1.z;a[7]=a1.w;
      float4 b0 = *(const float4*)&Bs[kk][tx*8];
      float4 b1 = *(const float4*)&Bs[kk][tx*8+4];
      b[0]=b0.x;b[1]=b0.y;b[2]=b0.z;b[3]=b0.w;
      b[4]=b1.x;b[5]=b1.y;b[6]=b1.z;b[7]=b1.w;
#pragma unroll
      for(int i=0;i<8;++i)
#pragma unroll
        for(int j=0;j<8;++j)
          acc[i][j] = fmaf(a[i], b[j], acc[i][j]);
    }
    __syncthreads();
  }
#pragma unroll
  for(int i=0;i<8;++i){
    int gr = row0 + ty*8 + i;
    if (gr >= M) continue;
    size_t rb = (size_t)gr * Nw;
#pragma unroll
    for(int j=0;j<8;++j){
      int gc = col0 + tx*8 + j;
      out[rb+gc] = acc[i][j] + bias[gc];
    }
  }
}

// ---------------- LayerNorm -> split bf16 planes ---------------------------------
__global__ __launch_bounds__(256) void ln_split_kernel(const float* __restrict__ in,
    const float* __restrict__ g, const float* __restrict__ b,
    unsigned short* __restrict__ outh, unsigned short* __restrict__ outl, float eps)
{
  int r = blockIdx.x;
  int tid = threadIdx.x;
  const float* rp = in + (size_t)r * D_;
  float2 v = *(const float2*)(rp + tid*2);
  float s = v.x + v.y;
  float q = v.x*v.x + v.y*v.y;
  s = wave_sum(s); q = wave_sum(q);
  __shared__ float ss[4], qq[4];
  int wid = tid >> 6, lane = tid & 63;
  if(lane==0){ ss[wid]=s; qq[wid]=q; }
  __syncthreads();
  float S = ss[0]+ss[1]+ss[2]+ss[3];
  float Q = qq[0]+qq[1]+qq[2]+qq[3];
  float mean = S * (1.f/D_);
  float var = Q * (1.f/D_) - mean*mean;
  float rstd = rsqrtf(var + eps);
  int d = tid*2;
  float o0 = (v.x-mean)*rstd*g[d]   + b[d];
  float o1 = (v.y-mean)*rstd*g[d+1] + b[d+1];
  unsigned short h0,l0,h1,l1;
  split2(o0,h0,l0); split2(o1,h1,l1);
  *(ushort2*)(outh + (size_t)r*D_ + d) = make_ushort2(h0,h1);
  *(ushort2*)(outl + (size_t)r*D_ + d) = make_ushort2(l0,l1);
}

// ---------------- q post (f32, in place) -----------------------------------------
__global__ __launch_bounds__(256) void qs_post_kernel(float* __restrict__ q,
                                                      const float* __restrict__ temp)
{
  int tid = threadIdx.x;
  int gid = blockIdx.x*4 + (tid>>6);
  int dd  = tid & 63;
  int h = gid % H_;
  int n = (gid / H_) % N_;
  int b = gid / (H_*N_);
  size_t idx = ((size_t)(b*N_+n))*D_ + h*HD_ + dd;
  float v = q[idx];
  float ss = wave_sum(v*v);
  v = v / fmaxf(sqrtf(ss), 1e-12f);
  float t = temp[h];
  float sp = log1pf(expf(t));
  v *= sp * 2.77258872223978124f;
  float partner = __shfl_xor(v, 32);
  int i = dd & 31;
  float inv = 1.f / powf(10000.f, (float)i * (1.f/32.f));
  float ang = (float)n * inv;
  float s, c; sincosf(ang, &s, &c);
  q[idx] = (dd < 32) ? fmaf(v, c, -partner*s) : fmaf(partner, s, v*c);
}

// ---------------- k post ---------------------------------------------------------
__global__ __launch_bounds__(256) void k_post_kernel(const float* __restrict__ kvb,
                                                     float* __restrict__ kln)
{
  int tid = threadIdx.x;
  int gid = blockIdx.x*4 + (tid>>6);
  int dd  = tid & 63;
  int h = gid % H_;
  int n = (gid / H_) % N_;
  int b = gid / (H_*N_);
  float v = kvb[((size_t)(b*N_+n))*(2*D_) + h*HD_ + dd];
  float partner = __shfl_xor(v, 32);
  int i = dd & 31;
  float inv = 1.f / powf(10000.f, (float)i * (1.f/32.f));
  float ang = (float)n * inv;
  float s, c; sincosf(ang, &s, &c);
  float r = (dd < 32) ? fmaf(v, c, -partner*s) : fmaf(partner, s, v*c);
  float ss = wave_sum(r*r);
  r = r / fmaxf(sqrtf(ss), 1e-12f);
  kln[((size_t)(b*N_+n))*D_ + h*HD_ + dd] = r;
}

// ---------------- pooled path ----------------------------------------------------
__global__ __launch_bounds__(256) void pool_ln_kernel(const float* __restrict__ src,
    const float* __restrict__ g, const float* __restrict__ b, float* __restrict__ xp)
{
  int bp = blockIdx.x;
  int bb = bp / P_, p = bp % P_;
  int tid = threadIdx.x;
  const float* base = src + ((size_t)(bb*N_ + p*(N_/P_)))*D_;
  float a0=0.f, a1=0.f;
  for(int i=0;i<N_/P_;++i){
    a0 += base[(size_t)i*D_ + tid];
    a1 += base[(size_t)i*D_ + tid + 256];
  }
  a0 *= (1.f/(N_/P_)); a1 *= (1.f/(N_/P_));
  float s = a0+a1, q = a0*a0+a1*a1;
  s = wave_sum(s); q = wave_sum(q);
  __shared__ float ss[4], qq[4];
  int wid = tid>>6, lane = tid&63;
  if(lane==0){ ss[wid]=s; qq[wid]=q; }
  __syncthreads();
  float S = ss[0]+ss[1]+ss[2]+ss[3];
  float Q = qq[0]+qq[1]+qq[2]+qq[3];
  float mean = S*(1.f/D_);
  float var  = Q*(1.f/D_) - mean*mean;
  float rstd = rsqrtf(var + 1e-5f);
  xp[(size_t)bp*D_ + tid]       = (a0-mean)*rstd*g[tid]     + b[tid];
  xp[(size_t)bp*D_ + tid + 256] = (a1-mean)*rstd*g[tid+256] + b[tid+256];
}

// ---------------- kP rope --------------------------------------------------------
__global__ __launch_bounds__(512) void kp_rope_kernel(const float* __restrict__ kvp,
                                                      float* __restrict__ kpb)
{
  int bp = blockIdx.x;
  int d  = threadIdx.x;
  int dd = d & 63;
  int p  = bp % P_;
  float v = kvp[(size_t)bp*(2*D_) + d];
  float partner = __shfl_xor(v, 32);
  int i = dd & 31;
  float inv = 1.f / powf(10000.f, (float)i * (1.f/32.f));
  float ang = (float)p * inv;
  float s, c; sincosf(ang, &s, &c);
  kpb[(size_t)bp*D_ + d] = (dd < 32) ? fmaf(v, c, -partner*s) : fmaf(partner, s, v*c);
}

// ---------------- attention -> split bf16 attn_out -------------------------------
__global__ __launch_bounds__(256) void attn_kernel(
    const float* __restrict__ qs, const float* __restrict__ kln,
    const float* __restrict__ kvb, const float* __restrict__ kpb,
    const float* __restrict__ kvp,
    unsigned short* __restrict__ outh, unsigned short* __restrict__ outl)
{
  int tid = threadIdx.x;
  int gid = blockIdx.x*4 + (tid>>6);
  int dd  = tid & 63;
  int h = gid % H_;
  int n = (gid / H_) % N_;
  int b = gid / (H_*N_);
  size_t tok = (size_t)(b*N_+n);
  float qv = qs[tok*D_ + h*HD_ + dd];
  float l[KW_+P_];
#pragma unroll
  for(int j=0;j<KW_;++j){
    int np  = n - KW_/2 + j;
    int npc = min(max(np,0), N_-1);
    float kd = kln[((size_t)(b*N_+npc))*D_ + h*HD_ + dd];
    float sdot = wave_sum(qv*kd);
    l[j] = (np>=0 && np<N_) ? sdot : -3.0e38f;
  }
#pragma unroll
  for(int p=0;p<P_;++p){
    float kd = kpb[((size_t)(b*P_+p))*D_ + h*HD_ + dd];
    l[KW_+p] = wave_sum(qv*kd);
  }
  float m = l[0];
#pragma unroll
  for(int j=1;j<KW_+P_;++j) m = fmaxf(m, l[j]);
  float a[KW_+P_]; float sum = 0.f;
#pragma unroll
  for(int j=0;j<KW_+P_;++j){ a[j] = expf(l[j]-m); sum += a[j]; }
  float inv = 1.f / sum;
  float o = 0.f;
#pragma unroll
  for(int j=0;j<KW_;++j){
    int npc = min(max(n - KW_/2 + j, 0), N_-1);
    o = fmaf(a[j], kvb[((size_t)(b*N_+npc))*(2*D_) + D_ + h*HD_ + dd], o);
  }
#pragma unroll
  for(int p=0;p<P_;++p){
    o = fmaf(a[KW_+p], kvp[((size_t)(b*P_+p))*(2*D_) + D_ + h*HD_ + dd], o);
  }
  unsigned short wh, wl;
  split2(o * inv, wh, wl);
  outh[tok*D_ + h*HD_ + dd] = wh;
  outl[tok*D_ + h*HD_ + dd] = wl;
}

// ---------------- router + stats (reads split xn2) -------------------------------
__global__ void zero_stats_kernel(float* stats){
  if(threadIdx.x < 16) stats[threadIdx.x] = 0.f;
}

__global__ __launch_bounds__(256) void router_kernel(
    const unsigned short* __restrict__ xh, const unsigned short* __restrict__ xl,
    const float* __restrict__ rw, const float* __restrict__ rb,
    float* __restrict__ gates, float* __restrict__ stats)
{
  int tid = threadIdx.x;
  int wid = tid>>6, lane = tid&63;
  int t = blockIdx.x*4 + wid;
  float a0=0.f,a1=0.f,a2=0.f,a3=0.f;
  for(int k=lane;k<D_;k+=64){
    float xv = bf2f(xh[(size_t)t*D_+k]) + bf2f(xl[(size_t)t*D_+k]);
    float4 w = *(const float4*)(rw + (size_t)k*E_);
    a0 = fmaf(xv,w.x,a0); a1 = fmaf(xv,w.y,a1);
    a2 = fmaf(xv,w.z,a2); a3 = fmaf(xv,w.w,a3);
  }
  a0=wave_sum(a0); a1=wave_sum(a1); a2=wave_sum(a2); a3=wave_sum(a3);
  __shared__ float sg[4][E_], sc[4][E_];
  if(lane==0){
    float lg[E_] = {a0+rb[0], a1+rb[1], a2+rb[2], a3+rb[3]};
    float m = fmaxf(fmaxf(lg[0],lg[1]), fmaxf(lg[2],lg[3]));
    float e[E_]; float sum=0.f;
#pragma unroll
    for(int k=0;k<E_;++k){ e[k]=expf(lg[k]-m); sum+=e[k]; }
    float inv = 1.f/sum;
    int am = 0; float bv = lg[0];
#pragma unroll
    for(int k=1;k<E_;++k) if(lg[k] > bv){ bv = lg[k]; am = k; }
#pragma unroll
    for(int k=0;k<E_;++k){
      float gk = e[k]*inv;
      gates[(size_t)t*E_ + k] = gk;
      sg[wid][k] = gk;
      sc[wid][k] = (k==am) ? 1.f : 0.f;
    }
  }
  __syncthreads();
  if(tid < E_){
    atomicAdd(stats + tid,      sc[0][tid]+sc[1][tid]+sc[2][tid]+sc[3][tid]);
    atomicAdd(stats + E_ + tid, sg[0][tid]+sg[1][tid]+sg[2][tid]+sg[3][tid]);
  }
}

__global__ void aux_kernel(const float* __restrict__ stats, float* __restrict__ outp){
  float acc = 0.f;
  const float inv = 1.f / (float)TOK_;
#pragma unroll
  for(int e=0;e<E_;++e) acc += (stats[e]*inv) * (stats[E_+e]*inv);
  *outp = 0.01f * (float)E_ * acc;
}

// =================================================================================
extern "C" void kernel_launch(void* const* d_in, const int* in_sizes, int n_in,
                              void* d_out, int out_size, void* d_ws, size_t ws_size,
                              hipStream_t stream)
{
  const float* x      = (const float*)d_in[0];
  const float* temp   = (const float*)d_in[1];
  const float* q_w    = (const float*)d_in[2];
  const float* q_b    = (const float*)d_in[3];
  const float* kv_w   = (const float*)d_in[4];
  const float* kv_b   = (const float*)d_in[5];
  const float* proj_w = (const float*)d_in[6];
  const float* proj_b = (const float*)d_in[7];
  const float* n1g    = (const float*)d_in[8];
  const float* n1b    = (const float*)d_in[9];
  const float* n2g    = (const float*)d_in[10];
  const float* n2b    = (const float*)d_in[11];
  const float* sr_w   = (const float*)d_in[12];
  const float* sr_b   = (const float*)d_in[13];
  const float* npg    = (const float*)d_in[14];
  const float* npb    = (const float*)d_in[15];
  const float* rw     = (const float*)d_in[16];
  const float* rb     = (const float*)d_in[17];
  const float* ew1    = (const float*)d_in[18];
  const float* eb1    = (const float*)d_in[19];
  const float* ew2    = (const float*)d_in[20];
  const float* eb2    = (const float*)d_in[21];
  const float* sw1    = (const float*)d_in[22];
  const float* sb1    = (const float*)d_in[23];
  const float* sw2    = (const float*)d_in[24];
  const float* sb2    = (const float*)d_in[25];

  float* out = (float*)d_out;
  const size_t S = (size_t)TOK_ * D_;          // 4,194,304
  char* base = (char*)d_ws;
  size_t off = 0;
  auto aus = [&](size_t n)->unsigned short*{ unsigned short* p=(unsigned short*)(base+off); off += n*2; return p; };
  auto af  = [&](size_t n)->float*{ float* p=(float*)(base+off); off += n*4; return p; };

  // persistent weight planes (transposed [N][K])
  unsigned short *qwh = aus(512*512),  *qwl = aus(512*512);
  unsigned short *kvwh= aus(512*1024), *kvwl= aus(512*1024);
  unsigned short *srwh= aus(512*512),  *srwl= aus(512*512);
  unsigned short *pjwh= aus(512*512),  *pjwl= aus(512*512);
  unsigned short *s1h = aus(512*2048), *s1l = aus(512*2048);
  unsigned short *s2h = aus(2048*512), *s2l = aus(2048*512);
  unsigned short *e1h = aus((size_t)E_*512*2048), *e1l = aus((size_t)E_*512*2048);
  unsigned short *e2h = aus((size_t)E_*2048*512), *e2l = aus((size_t)E_*2048*512);
  // xn planes (reused later as xn2 planes)
  unsigned short *xnh = aus(S), *xnl = aus(S);
  // f32 region: qsb + kvb + kln (reused later as hid planes, exactly 4S elems x2)
  float* qsb = af(S);
  float* kvb = af(2*S);
  float* kln = af(S);
  unsigned short* hidh = (unsigned short*)qsb;
  unsigned short* hidl = hidh + 4*S;
  // srg f32 (reused later as attn_out planes)
  float* srg = af(S);
  unsigned short* atth = (unsigned short*)srg;
  unsigned short* attl = atth + S;
  // small tail
  float* xp    = af((size_t)B_*P_*D_);
  float* kvp   = af((size_t)B_*P_*2*D_);
  float* kpb   = af((size_t)B_*P_*D_);
  float* gates = af((size_t)TOK_*E_);
  float* stats = af(16);

  // 0. weight convert+transpose+split
  wconv_kernel<<<dim3(8,8,1),  256, 0, stream>>>(q_w,    qwh, qwl, 512, 512);
  wconv_kernel<<<dim3(16,8,1), 256, 0, stream>>>(kv_w,   kvwh,kvwl,512, 1024);
  wconv_kernel<<<dim3(8,8,1),  256, 0, stream>>>(sr_w,   srwh,srwl,512, 512);
  wconv_kernel<<<dim3(8,8,1),  256, 0, stream>>>(proj_w, pjwh,pjwl,512, 512);
  wconv_kernel<<<dim3(32,8,1), 256, 0, stream>>>(sw1,    s1h, s1l, 512, 2048);
  wconv_kernel<<<dim3(8,32,1), 256, 0, stream>>>(sw2,    s2h, s2l, 2048,512);
  wconv_kernel<<<dim3(32,8,E_),256, 0, stream>>>(ew1,    e1h, e1l, 512, 2048);
  wconv_kernel<<<dim3(8,32,E_),256, 0, stream>>>(ew2,    e2h, e2l, 2048,512);

  // 1. xn = LN1(x) -> split planes
  ln_split_kernel<<<dim3(TOK_), 256, 0, stream>>>(x, n1g, n1b, xnh, xnl, 1e-6f);
  // 2. q = xn @ q_w + q_b (f32 out)
  gemm_mfma<GEPI_PLAIN><<<dim3(4,64), 256, 0, stream>>>(xnh,xnl,qwh,qwl,q_b, qsb,nullptr,nullptr, TOK_,512,512, nullptr,nullptr,0);
  // 3. kv = xn @ kv_w + kv_b
  gemm_mfma<GEPI_PLAIN><<<dim3(8,64), 256, 0, stream>>>(xnh,xnl,kvwh,kvwl,kv_b, kvb,nullptr,nullptr, TOK_,512,1024, nullptr,nullptr,0);
  // 4. srg = gelu(xn @ sr_w + sr_b) (f32, pooling source)
  gemm_mfma<GEPI_GELU_F32><<<dim3(4,64), 256, 0, stream>>>(xnh,xnl,srwh,srwl,sr_b, srg,nullptr,nullptr, TOK_,512,512, nullptr,nullptr,0);
  // 5. xp = LN(mean-pool)
  pool_ln_kernel<<<dim3(B_*P_), 256, 0, stream>>>(srg, npg, npb, xp);
  // 6. kvp = xp @ kv_w + kv_b (tiny, f32 vector path)
  gemm_f32<EPI_PLAIN><<<dim3(8,1), 256, 0, stream>>>(xp, kv_w, kv_b, kvp, B_*P_, 512, 1024, nullptr, nullptr, 0);
  // 7. kP = rope(kvp[:, :D])
  kp_rope_kernel<<<dim3(B_*P_), 512, 0, stream>>>(kvp, kpb);
  // 8. qs post
  qs_post_kernel<<<dim3(B_*N_*H_/4), 256, 0, stream>>>(qsb, temp);
  // 9. kln
  k_post_kernel<<<dim3(B_*N_*H_/4), 256, 0, stream>>>(kvb, kln);
  // 10. attention -> split attn_out
  attn_kernel<<<dim3(B_*H_*N_/4), 256, 0, stream>>>(qsb, kln, kvb, kpb, kvp, atth, attl);
  // 11. out = x + attn_out @ proj_w + proj_b
  gemm_mfma<GEPI_RESID><<<dim3(4,64), 256, 0, stream>>>(atth,attl,pjwh,pjwl,proj_b, out,nullptr,nullptr, TOK_,512,512, x,nullptr,0);
  // 12. xn2 = LN2(out) -> split planes (reuse xn region)
  ln_split_kernel<<<dim3(TOK_), 256, 0, stream>>>(out, n2g, n2b, xnh, xnl, 1e-6f);
  // 13-14. router + stats
  zero_stats_kernel<<<dim3(1), 64, 0, stream>>>(stats);
  router_kernel<<<dim3(TOK_/4), 256, 0, stream>>>(xnh, xnl, rw, rb, gates, stats);
  // 15. MoE (hid planes reuse qsb/kvb/kln region)
  gemm_mfma<GEPI_GELU_HILO><<<dim3(16,64), 256, 0, stream>>>(xnh,xnl,s1h,s1l,sb1, nullptr,hidh,hidl, TOK_,512,HID_, nullptr,nullptr,0);
  gemm_mfma<GEPI_ACC><<<dim3(4,64), 256, 0, stream>>>(hidh,hidl,s2h,s2l,sb2, out,nullptr,nullptr, TOK_,HID_,512, nullptr,nullptr,0);
  for(int e=0;e<E_;++e){
    gemm_mfma<GEPI_GELU_HILO><<<dim3(16,64), 256, 0, stream>>>(xnh,xnl, e1h+(size_t)e*512*2048, e1l+(size_t)e*512*2048, eb1+(size_t)e*HID_, nullptr,hidh,hidl, TOK_,512,HID_, nullptr,nullptr,0);
    gemm_mfma<GEPI_ACC><<<dim3(4,64), 256, 0, stream>>>(hidh,hidl, e2h+(size_t)e*2048*512, e2l+(size_t)e*2048*512, eb2+(size_t)e*D_, out,nullptr,nullptr, TOK_,HID_,512, nullptr,gates+e,E_);
  }
  // 16. aux scalar
  aux_kernel<<<dim3(1), 1, 0, stream>>>(stats, out + S);
}

// Round 7
// 1287.970 us; speedup vs baseline: 2.7272x; 1.1120x over previous
//
#include <hip/hip_runtime.h>
#include <hip/hip_bf16.h>
#include <math.h>

#define B_ 4
#define N_ 2048
#define D_ 512
#define H_ 8
#define HD_ 64
#define KW_ 9
#define P_ 8
#define E_ 4
#define HID_ 2048
#define TOK_ (B_*N_)   // 8192

typedef __bf16 bf16x8 __attribute__((ext_vector_type(8)));
typedef float  f32x4  __attribute__((ext_vector_type(4)));

static __device__ __forceinline__ float wave_sum(float v){
#pragma unroll
  for(int off=32; off>0; off>>=1) v += __shfl_xor(v, off);
  return v;
}

static __device__ __forceinline__ float gelu_exact(float v){
  return 0.5f * v * (1.f + erff(v * 0.70710678118654752440f));
}

// split f32 into hi+lo bf16 (3-term MFMA gives ~f32 product precision)
static __device__ __forceinline__ void split2(float v, unsigned short& h, unsigned short& l){
  __bf16 bh = (__bf16)v;
  float r = v - (float)bh;
  __bf16 bl = (__bf16)r;
  h = __builtin_bit_cast(unsigned short, bh);
  l = __builtin_bit_cast(unsigned short, bl);
}
static __device__ __forceinline__ float bf2f(unsigned short u){
  return (float)__builtin_bit_cast(__bf16, u);
}

// async global->LDS, 16B per lane, LDS dest = wave-uniform base + lane*16
static __device__ __forceinline__ void gload16(const unsigned short* g, unsigned short* l){
  __builtin_amdgcn_global_load_lds(
      (const __attribute__((address_space(1))) unsigned int*)g,
      (__attribute__((address_space(3))) unsigned int*)l, 16, 0, 0);
}

// ---------------- weight convert: W f32 [K][N] -> Wt hi/lo bf16 [N][K] ----------
__global__ __launch_bounds__(256) void wconv_kernel(const float* __restrict__ W,
    unsigned short* __restrict__ Th, unsigned short* __restrict__ Tl, int K, int N)
{
  size_t ms = (size_t)K*N;
  const float* Wb = W + blockIdx.z*ms;
  unsigned short* Thb = Th + blockIdx.z*ms;
  unsigned short* Tlb = Tl + blockIdx.z*ms;
  __shared__ float tile[64][65];
  int n0 = blockIdx.x*64, k0 = blockIdx.y*64;
  int t = threadIdx.x;
  int c4 = (t&15)*4, r = t>>4;
#pragma unroll
  for(int pass=0; pass<4; ++pass){
    int k = r + pass*16;
    float4 v = *(const float4*)(Wb + (size_t)(k0+k)*N + n0 + c4);
    tile[k][c4]=v.x; tile[k][c4+1]=v.y; tile[k][c4+2]=v.z; tile[k][c4+3]=v.w;
  }
  __syncthreads();
#pragma unroll
  for(int pass=0; pass<4; ++pass){
    int n = r + pass*16;
    unsigned short h0,h1,h2,h3,l0,l1,l2,l3;
    split2(tile[c4+0][n], h0, l0);
    split2(tile[c4+1][n], h1, l1);
    split2(tile[c4+2][n], h2, l2);
    split2(tile[c4+3][n], h3, l3);
    *(ushort4*)(Thb + (size_t)(n0+n)*K + k0 + c4) = make_ushort4(h0,h1,h2,h3);
    *(ushort4*)(Tlb + (size_t)(n0+n)*K + k0 + c4) = make_ushort4(l0,l1,l2,l3);
  }
}

// ---------------- split-bf16 MFMA GEMM, global_load_lds staging (m97 recipe) -----
// A [M][K] bf16 planes, Bt [N][K] bf16 planes. Tile 128x128, BK=64, 4 waves.
// Linear LDS (T2 swizzle null at 2-phase per regime-gate); wave w stages plane w.
#define GEPI_PLAIN     0
#define GEPI_GELU_F32  1
#define GEPI_RESID     2
#define GEPI_ACC       3
#define GEPI_GELU_HILO 4

template<int EPI>
__global__ __launch_bounds__(256,2) void gemm_mfma(
    const unsigned short* __restrict__ Ah, const unsigned short* __restrict__ Al,
    const unsigned short* __restrict__ Bh, const unsigned short* __restrict__ Bl,
    const float* __restrict__ bias,
    float* __restrict__ out, unsigned short* __restrict__ outh, unsigned short* __restrict__ outl,
    int M, int K, int N,
    const float* __restrict__ resid, const float* __restrict__ gate, int gstride)
{
  __shared__ unsigned short lds[4][128][64];   // Ah,Al,Bh,Bl tiles; 64 KB
  int tid = threadIdx.x;
  int lane = tid & 63, w = tid >> 6;
  int wm = w >> 1, wn = w & 1;
  int row0 = blockIdx.y*128, col0 = blockIdx.x*128;
  int r15 = lane & 15, g = lane >> 4;
  // wave w stages plane w: per-lane global row/col offsets
  const unsigned short* Pb;
  if      (w==0) Pb = Ah + (size_t)row0*K;
  else if (w==1) Pb = Al + (size_t)row0*K;
  else if (w==2) Pb = Bh + (size_t)col0*K;
  else           Pb = Bl + (size_t)col0*K;
  const unsigned short* Pl = Pb + (size_t)(lane>>3)*K + (lane&7)*8;

  f32x4 acc[4][4];
#pragma unroll
  for(int i=0;i<4;++i)
#pragma unroll
    for(int j=0;j<4;++j) acc[i][j] = (f32x4){0.f,0.f,0.f,0.f};

  for(int k0=0; k0<K; k0+=64){
    __syncthreads();             // prior compute done before overwrite
#pragma unroll
    for(int c=0;c<16;++c){
      gload16(Pl + (size_t)(c*8)*K + k0, &lds[w][c*8][0]);
    }
    __syncthreads();             // drains vmcnt(0): all planes staged
#pragma unroll
    for(int ks=0; ks<2; ++ks){
      bf16x8 afh[4], afl[4], bfh[4], bfl[4];
#pragma unroll
      for(int mf=0; mf<4; ++mf){
        int row = wm*64 + mf*16 + r15;
        afh[mf] = *(const bf16x8*)&lds[0][row][(ks*4+g)*8];
        afl[mf] = *(const bf16x8*)&lds[1][row][(ks*4+g)*8];
      }
#pragma unroll
      for(int nf=0; nf<4; ++nf){
        int row = wn*64 + nf*16 + r15;
        bfh[nf] = *(const bf16x8*)&lds[2][row][(ks*4+g)*8];
        bfl[nf] = *(const bf16x8*)&lds[3][row][(ks*4+g)*8];
      }
#pragma unroll
      for(int mf=0; mf<4; ++mf)
#pragma unroll
        for(int nf=0; nf<4; ++nf){
          acc[mf][nf] = __builtin_amdgcn_mfma_f32_16x16x32_bf16(afh[mf], bfh[nf], acc[mf][nf], 0,0,0);
          acc[mf][nf] = __builtin_amdgcn_mfma_f32_16x16x32_bf16(afh[mf], bfl[nf], acc[mf][nf], 0,0,0);
          acc[mf][nf] = __builtin_amdgcn_mfma_f32_16x16x32_bf16(afl[mf], bfh[nf], acc[mf][nf], 0,0,0);
        }
    }
  }
  // epilogue: D col = lane&15 (N), row = (lane>>4)*4 + v (M)
#pragma unroll
  for(int mf=0; mf<4; ++mf){
#pragma unroll
    for(int nf=0; nf<4; ++nf){
      int col = col0 + wn*64 + nf*16 + r15;
      float bv = bias[col];
#pragma unroll
      for(int v=0; v<4; ++v){
        int row = row0 + wm*64 + mf*16 + g*4 + v;
        size_t o = (size_t)row*N + col;
        float val = acc[mf][nf][v] + bv;
        if      (EPI == GEPI_GELU_F32){ out[o] = gelu_exact(val); }
        else if (EPI == GEPI_GELU_HILO){
          float gv = gelu_exact(val);
          unsigned short hh, ll; split2(gv, hh, ll);
          outh[o] = hh; outl[o] = ll;
        }
        else if (EPI == GEPI_RESID){ out[o] = val + resid[o]; }
        else if (EPI == GEPI_ACC){
          float gv = gate ? gate[(size_t)row*gstride] : 1.f;
          out[o] += gv * val;
        }
        else { out[o] = val; }
      }
    }
  }
}

// ---------------- legacy f32 vector GEMM (only for the tiny 32-row kvp GEMM) -----
#define EPI_PLAIN 0
template<int EPI>
__global__ __launch_bounds__(256) void gemm_f32(
    const float* __restrict__ A, const float* __restrict__ W,
    const float* __restrict__ bias, float* __restrict__ out,
    int M, int Kd, int Nw,
    const float* __restrict__ resid,
    const float* __restrict__ gate, int gstride)
{
  __shared__ __align__(16) float As[16][128];
  __shared__ __align__(16) float Bs[16][128];
  int tid = threadIdx.x;
  int tx = tid & 15, ty = tid >> 4;
  int row0 = blockIdx.y * 128, col0 = blockIdx.x * 128;
  float acc[8][8];
#pragma unroll
  for(int i=0;i<8;++i)
#pragma unroll
    for(int j=0;j<8;++j) acc[i][j]=0.f;

  for(int k0=0; k0<Kd; k0+=16){
#pragma unroll
    for(int i=0;i<2;++i){
      int f4 = tid*2+i;
      int r  = f4 >> 2;
      int kc = (f4 & 3) << 2;
      int gr = row0 + r;
      float4 v = make_float4(0.f,0.f,0.f,0.f);
      if (gr < M) v = *(const float4*)(A + (size_t)gr*Kd + k0 + kc);
      As[kc+0][r]=v.x; As[kc+1][r]=v.y; As[kc+2][r]=v.z; As[kc+3][r]=v.w;
    }
#pragma unroll
    for(int i=0;i<2;++i){
      int f4 = tid*2+i;
      int kr = f4 >> 5;
      int c  = (f4 & 31) << 2;
      *(float4*)&Bs[kr][c] = *(const float4*)(W + (size_t)(k0+kr)*Nw + col0 + c);
    }
    __syncthreads();
#pragma unroll
    for(int kk=0;kk<16;++kk){
      float a[8], b[8];
      float4 a0 = *(const float4*)&As[kk][ty*8];
      float4 a1 = *(const float4*)&As[kk][ty*8+4];
      a[0]=a0.x;a[1]=a0.y;a[2]=a0.z;a[3]=a0.w;
      a[4]=a1.x;a[5]=a1.y;a[6]=a1.z;a[7]=a1.w;
      float4 b0 = *(const float4*)&Bs[kk][tx*8];
      float4 b1 = *(const float4*)&Bs[kk][tx*8+4];
      b[0]=b0.x;b[1]=b0.y;b[2]=b0.z;b[3]=b0.w;
      b[4]=b1.x;b[5]=b1.y;b[6]=b1.z;b[7]=b1.w;
#pragma unroll
      for(int i=0;i<8;++i)
#pragma unroll
        for(int j=0;j<8;++j)
          acc[i][j] = fmaf(a[i], b[j], acc[i][j]);
    }
    __syncthreads();
  }
#pragma unroll
  for(int i=0;i<8;++i){
    int gr = row0 + ty*8 + i;
    if (gr >= M) continue;
    size_t rb = (size_t)gr * Nw;
#pragma unroll
    for(int j=0;j<8;++j){
      int gc = col0 + tx*8 + j;
      out[rb+gc] = acc[i][j] + bias[gc];
    }
  }
}

// ---------------- LayerNorm -> split bf16 planes ---------------------------------
__global__ __launch_bounds__(256) void ln_split_kernel(const float* __restrict__ in,
    const float* __restrict__ g, const float* __restrict__ b,
    unsigned short* __restrict__ outh, unsigned short* __restrict__ outl, float eps)
{
  int r = blockIdx.x;
  int tid = threadIdx.x;
  const float* rp = in + (size_t)r * D_;
  float2 v = *(const float2*)(rp + tid*2);
  float s = v.x + v.y;
  float q = v.x*v.x + v.y*v.y;
  s = wave_sum(s); q = wave_sum(q);
  __shared__ float ss[4], qq[4];
  int wid = tid >> 6, lane = tid & 63;
  if(lane==0){ ss[wid]=s; qq[wid]=q; }
  __syncthreads();
  float S = ss[0]+ss[1]+ss[2]+ss[3];
  float Q = qq[0]+qq[1]+qq[2]+qq[3];
  float mean = S * (1.f/D_);
  float var = Q * (1.f/D_) - mean*mean;
  float rstd = rsqrtf(var + eps);
  int d = tid*2;
  float o0 = (v.x-mean)*rstd*g[d]   + b[d];
  float o1 = (v.y-mean)*rstd*g[d+1] + b[d+1];
  unsigned short h0,l0,h1,l1;
  split2(o0,h0,l0); split2(o1,h1,l1);
  *(ushort2*)(outh + (size_t)r*D_ + d) = make_ushort2(h0,h1);
  *(ushort2*)(outl + (size_t)r*D_ + d) = make_ushort2(l0,l1);
}

// ---------------- q post (f32, in place) -----------------------------------------
__global__ __launch_bounds__(256) void qs_post_kernel(float* __restrict__ q,
                                                      const float* __restrict__ temp)
{
  int tid = threadIdx.x;
  int gid = blockIdx.x*4 + (tid>>6);
  int dd  = tid & 63;
  int h = gid % H_;
  int n = (gid / H_) % N_;
  int b = gid / (H_*N_);
  size_t idx = ((size_t)(b*N_+n))*D_ + h*HD_ + dd;
  float v = q[idx];
  float ss = wave_sum(v*v);
  v = v / fmaxf(sqrtf(ss), 1e-12f);
  float t = temp[h];
  float sp = log1pf(expf(t));
  v *= sp * 2.77258872223978124f;
  float partner = __shfl_xor(v, 32);
  int i = dd & 31;
  float inv = 1.f / powf(10000.f, (float)i * (1.f/32.f));
  float ang = (float)n * inv;
  float s, c; sincosf(ang, &s, &c);
  q[idx] = (dd < 32) ? fmaf(v, c, -partner*s) : fmaf(partner, s, v*c);
}

// ---------------- k post ---------------------------------------------------------
__global__ __launch_bounds__(256) void k_post_kernel(const float* __restrict__ kvb,
                                                     float* __restrict__ kln)
{
  int tid = threadIdx.x;
  int gid = blockIdx.x*4 + (tid>>6);
  int dd  = tid & 63;
  int h = gid % H_;
  int n = (gid / H_) % N_;
  int b = gid / (H_*N_);
  float v = kvb[((size_t)(b*N_+n))*(2*D_) + h*HD_ + dd];
  float partner = __shfl_xor(v, 32);
  int i = dd & 31;
  float inv = 1.f / powf(10000.f, (float)i * (1.f/32.f));
  float ang = (float)n * inv;
  float s, c; sincosf(ang, &s, &c);
  float r = (dd < 32) ? fmaf(v, c, -partner*s) : fmaf(partner, s, v*c);
  float ss = wave_sum(r*r);
  r = r / fmaxf(sqrtf(ss), 1e-12f);
  kln[((size_t)(b*N_+n))*D_ + h*HD_ + dd] = r;
}

// ---------------- pooled path ----------------------------------------------------
__global__ __launch_bounds__(256) void pool_ln_kernel(const float* __restrict__ src,
    const float* __restrict__ g, const float* __restrict__ b, float* __restrict__ xp)
{
  int bp = blockIdx.x;
  int bb = bp / P_, p = bp % P_;
  int tid = threadIdx.x;
  const float* base = src + ((size_t)(bb*N_ + p*(N_/P_)))*D_;
  float a0=0.f, a1=0.f;
  for(int i=0;i<N_/P_;++i){
    a0 += base[(size_t)i*D_ + tid];
    a1 += base[(size_t)i*D_ + tid + 256];
  }
  a0 *= (1.f/(N_/P_)); a1 *= (1.f/(N_/P_));
  float s = a0+a1, q = a0*a0+a1*a1;
  s = wave_sum(s); q = wave_sum(q);
  __shared__ float ss[4], qq[4];
  int wid = tid>>6, lane = tid&63;
  if(lane==0){ ss[wid]=s; qq[wid]=q; }
  __syncthreads();
  float S = ss[0]+ss[1]+ss[2]+ss[3];
  float Q = qq[0]+qq[1]+qq[2]+qq[3];
  float mean = S*(1.f/D_);
  float var  = Q*(1.f/D_) - mean*mean;
  float rstd = rsqrtf(var + 1e-5f);
  xp[(size_t)bp*D_ + tid]       = (a0-mean)*rstd*g[tid]     + b[tid];
  xp[(size_t)bp*D_ + tid + 256] = (a1-mean)*rstd*g[tid+256] + b[tid+256];
}

// ---------------- kP rope --------------------------------------------------------
__global__ __launch_bounds__(512) void kp_rope_kernel(const float* __restrict__ kvp,
                                                      float* __restrict__ kpb)
{
  int bp = blockIdx.x;
  int d  = threadIdx.x;
  int dd = d & 63;
  int p  = bp % P_;
  float v = kvp[(size_t)bp*(2*D_) + d];
  float partner = __shfl_xor(v, 32);
  int i = dd & 31;
  float inv = 1.f / powf(10000.f, (float)i * (1.f/32.f));
  float ang = (float)p * inv;
  float s, c; sincosf(ang, &s, &c);
  kpb[(size_t)bp*D_ + d] = (dd < 32) ? fmaf(v, c, -partner*s) : fmaf(partner, s, v*c);
}

// ---------------- attention: 8-lane groups, lane holds 8 of 64 d-values ----------
static __device__ __forceinline__ float dot4(float4 a, float4 b){
  return fmaf(a.x,b.x, fmaf(a.y,b.y, fmaf(a.z,b.z, a.w*b.w)));
}

__global__ __launch_bounds__(256) void attn_kernel(
    const float* __restrict__ qs, const float* __restrict__ kln,
    const float* __restrict__ kvb, const float* __restrict__ kpb,
    const float* __restrict__ kvp,
    unsigned short* __restrict__ outh, unsigned short* __restrict__ outl)
{
  int tid = threadIdx.x;
  int gid = blockIdx.x*32 + (tid>>3);  // (b*N+n)*H + h
  int l   = tid & 7;
  int d0  = l*8;
  int h = gid % H_;
  int n = (gid / H_) % N_;
  int b = gid / (H_*N_);
  size_t tok = (size_t)(b*N_+n);
  const float* qp = qs + tok*D_ + h*HD_ + d0;
  float4 qa = *(const float4*)qp;
  float4 qb = *(const float4*)(qp+4);
  float lg[KW_+P_];
#pragma unroll
  for(int j=0;j<KW_;++j){
    int np  = n - KW_/2 + j;
    int npc = min(max(np,0), N_-1);
    const float* kp = kln + ((size_t)(b*N_+npc))*D_ + h*HD_ + d0;
    float4 ka = *(const float4*)kp;
    float4 kb = *(const float4*)(kp+4);
    float d = dot4(qa,ka) + dot4(qb,kb);
#pragma unroll
    for(int off=1; off<8; off<<=1) d += __shfl_xor(d, off);
    lg[j] = (np>=0 && np<N_) ? d : -3.0e38f;
  }
#pragma unroll
  for(int p=0;p<P_;++p){
    const float* kp = kpb + ((size_t)(b*P_+p))*D_ + h*HD_ + d0;
    float4 ka = *(const float4*)kp;
    float4 kb = *(const float4*)(kp+4);
    float d = dot4(qa,ka) + dot4(qb,kb);
#pragma unroll
    for(int off=1; off<8; off<<=1) d += __shfl_xor(d, off);
    lg[KW_+p] = d;
  }
  float m = lg[0];
#pragma unroll
  for(int j=1;j<KW_+P_;++j) m = fmaxf(m, lg[j]);
  float a[KW_+P_]; float sum = 0.f;
#pragma unroll
  for(int j=0;j<KW_+P_;++j){ a[j] = expf(lg[j]-m); sum += a[j]; }
  float inv = 1.f / sum;
  float4 oa = make_float4(0.f,0.f,0.f,0.f);
  float4 ob = make_float4(0.f,0.f,0.f,0.f);
#pragma unroll
  for(int j=0;j<KW_;++j){
    int npc = min(max(n - KW_/2 + j, 0), N_-1);
    const float* vp = kvb + ((size_t)(b*N_+npc))*(2*D_) + D_ + h*HD_ + d0;
    float4 va = *(const float4*)vp;
    float4 vb = *(const float4*)(vp+4);
    oa.x=fmaf(a[j],va.x,oa.x); oa.y=fmaf(a[j],va.y,oa.y); oa.z=fmaf(a[j],va.z,oa.z); oa.w=fmaf(a[j],va.w,oa.w);
    ob.x=fmaf(a[j],vb.x,ob.x); ob.y=fmaf(a[j],vb.y,ob.y); ob.z=fmaf(a[j],vb.z,ob.z); ob.w=fmaf(a[j],vb.w,ob.w);
  }
#pragma unroll
  for(int p=0;p<P_;++p){
    float w = a[KW_+p];
    const float* vp = kvp + ((size_t)(b*P_+p))*(2*D_) + D_ + h*HD_ + d0;
    float4 va = *(const float4*)vp;
    float4 vb = *(const float4*)(vp+4);
    oa.x=fmaf(w,va.x,oa.x); oa.y=fmaf(w,va.y,oa.y); oa.z=fmaf(w,va.z,oa.z); oa.w=fmaf(w,va.w,oa.w);
    ob.x=fmaf(w,vb.x,ob.x); ob.y=fmaf(w,vb.y,ob.y); ob.z=fmaf(w,vb.z,ob.z); ob.w=fmaf(w,vb.w,ob.w);
  }
  unsigned short h0,h1,h2,h3,l0,l1,l2,l3;
  size_t ob_ = tok*D_ + h*HD_ + d0;
  split2(oa.x*inv,h0,l0); split2(oa.y*inv,h1,l1); split2(oa.z*inv,h2,l2); split2(oa.w*inv,h3,l3);
  *(ushort4*)(outh + ob_)   = make_ushort4(h0,h1,h2,h3);
  *(ushort4*)(outl + ob_)   = make_ushort4(l0,l1,l2,l3);
  split2(ob.x*inv,h0,l0); split2(ob.y*inv,h1,l1); split2(ob.z*inv,h2,l2); split2(ob.w*inv,h3,l3);
  *(ushort4*)(outh + ob_+4) = make_ushort4(h0,h1,h2,h3);
  *(ushort4*)(outl + ob_+4) = make_ushort4(l0,l1,l2,l3);
}

// ---------------- router + stats (reads split xn2) -------------------------------
__global__ void zero_stats_kernel(float* stats){
  if(threadIdx.x < 16) stats[threadIdx.x] = 0.f;
}

__global__ __launch_bounds__(256) void router_kernel(
    const unsigned short* __restrict__ xh, const unsigned short* __restrict__ xl,
    const float* __restrict__ rw, const float* __restrict__ rb,
    float* __restrict__ gates, float* __restrict__ stats)
{
  int tid = threadIdx.x;
  int wid = tid>>6, lane = tid&63;
  int t = blockIdx.x*4 + wid;
  float a0=0.f,a1=0.f,a2=0.f,a3=0.f;
  for(int k=lane;k<D_;k+=64){
    float xv = bf2f(xh[(size_t)t*D_+k]) + bf2f(xl[(size_t)t*D_+k]);
    float4 w = *(const float4*)(rw + (size_t)k*E_);
    a0 = fmaf(xv,w.x,a0); a1 = fmaf(xv,w.y,a1);
    a2 = fmaf(xv,w.z,a2); a3 = fmaf(xv,w.w,a3);
  }
  a0=wave_sum(a0); a1=wave_sum(a1); a2=wave_sum(a2); a3=wave_sum(a3);
  __shared__ float sg[4][E_], sc[4][E_];
  if(lane==0){
    float lg[E_] = {a0+rb[0], a1+rb[1], a2+rb[2], a3+rb[3]};
    float m = fmaxf(fmaxf(lg[0],lg[1]), fmaxf(lg[2],lg[3]));
    float e[E_]; float sum=0.f;
#pragma unroll
    for(int k=0;k<E_;++k){ e[k]=expf(lg[k]-m); sum+=e[k]; }
    float inv = 1.f/sum;
    int am = 0; float bv = lg[0];
#pragma unroll
    for(int k=1;k<E_;++k) if(lg[k] > bv){ bv = lg[k]; am = k; }
#pragma unroll
    for(int k=0;k<E_;++k){
      float gk = e[k]*inv;
      gates[(size_t)t*E_ + k] = gk;
      sg[wid][k] = gk;
      sc[wid][k] = (k==am) ? 1.f : 0.f;
    }
  }
  __syncthreads();
  if(tid < E_){
    atomicAdd(stats + tid,      sc[0][tid]+sc[1][tid]+sc[2][tid]+sc[3][tid]);
    atomicAdd(stats + E_ + tid, sg[0][tid]+sg[1][tid]+sg[2][tid]+sg[3][tid]);
  }
}

__global__ void aux_kernel(const float* __restrict__ stats, float* __restrict__ outp){
  float acc = 0.f;
  const float inv = 1.f / (float)TOK_;
#pragma unroll
  for(int e=0;e<E_;++e) acc += (stats[e]*inv) * (stats[E_+e]*inv);
  *outp = 0.01f * (float)E_ * acc;
}

// =================================================================================
extern "C" void kernel_launch(void* const* d_in, const int* in_sizes, int n_in,
                              void* d_out, int out_size, void* d_ws, size_t ws_size,
                              hipStream_t stream)
{
  const float* x      = (const float*)d_in[0];
  const float* temp   = (const float*)d_in[1];
  const float* q_w    = (const float*)d_in[2];
  const float* q_b    = (const float*)d_in[3];
  const float* kv_w   = (const float*)d_in[4];
  const float* kv_b   = (const float*)d_in[5];
  const float* proj_w = (const float*)d_in[6];
  const float* proj_b = (const float*)d_in[7];
  const float* n1g    = (const float*)d_in[8];
  const float* n1b    = (const float*)d_in[9];
  const float* n2g    = (const float*)d_in[10];
  const float* n2b    = (const float*)d_in[11];
  const float* sr_w   = (const float*)d_in[12];
  const float* sr_b   = (const float*)d_in[13];
  const float* npg    = (const float*)d_in[14];
  const float* npb    = (const float*)d_in[15];
  const float* rw     = (const float*)d_in[16];
  const float* rb     = (const float*)d_in[17];
  const float* ew1    = (const float*)d_in[18];
  const float* eb1    = (const float*)d_in[19];
  const float* ew2    = (const float*)d_in[20];
  const float* eb2    = (const float*)d_in[21];
  const float* sw1    = (const float*)d_in[22];
  const float* sb1    = (const float*)d_in[23];
  const float* sw2    = (const float*)d_in[24];
  const float* sb2    = (const float*)d_in[25];

  float* out = (float*)d_out;
  const size_t S = (size_t)TOK_ * D_;          // 4,194,304
  char* base = (char*)d_ws;
  size_t off = 0;
  auto aus = [&](size_t n)->unsigned short*{ unsigned short* p=(unsigned short*)(base+off); off += n*2; return p; };
  auto af  = [&](size_t n)->float*{ float* p=(float*)(base+off); off += n*4; return p; };

  // persistent weight planes (transposed [N][K])
  unsigned short *qwh = aus(512*512),  *qwl = aus(512*512);
  unsigned short *kvwh= aus(512*1024), *kvwl= aus(512*1024);
  unsigned short *srwh= aus(512*512),  *srwl= aus(512*512);
  unsigned short *pjwh= aus(512*512),  *pjwl= aus(512*512);
  unsigned short *s1h = aus(512*2048), *s1l = aus(512*2048);
  unsigned short *s2h = aus(2048*512), *s2l = aus(2048*512);
  unsigned short *e1h = aus((size_t)E_*512*2048), *e1l = aus((size_t)E_*512*2048);
  unsigned short *e2h = aus((size_t)E_*2048*512), *e2l = aus((size_t)E_*2048*512);
  // xn planes (reused later as xn2 planes)
  unsigned short *xnh = aus(S), *xnl = aus(S);
  // f32 region: qsb + kvb + kln (reused later as hid planes, exactly 4S elems x2)
  float* qsb = af(S);
  float* kvb = af(2*S);
  float* kln = af(S);
  unsigned short* hidh = (unsigned short*)qsb;
  unsigned short* hidl = hidh + 4*S;
  // srg f32 (reused later as attn_out planes)
  float* srg = af(S);
  unsigned short* atth = (unsigned short*)srg;
  unsigned short* attl = atth + S;
  // small tail
  float* xp    = af((size_t)B_*P_*D_);
  float* kvp   = af((size_t)B_*P_*2*D_);
  float* kpb   = af((size_t)B_*P_*D_);
  float* gates = af((size_t)TOK_*E_);
  float* stats = af(16);

  // 0. weight convert+transpose+split
  wconv_kernel<<<dim3(8,8,1),  256, 0, stream>>>(q_w,    qwh, qwl, 512, 512);
  wconv_kernel<<<dim3(16,8,1), 256, 0, stream>>>(kv_w,   kvwh,kvwl,512, 1024);
  wconv_kernel<<<dim3(8,8,1),  256, 0, stream>>>(sr_w,   srwh,srwl,512, 512);
  wconv_kernel<<<dim3(8,8,1),  256, 0, stream>>>(proj_w, pjwh,pjwl,512, 512);
  wconv_kernel<<<dim3(32,8,1), 256, 0, stream>>>(sw1,    s1h, s1l, 512, 2048);
  wconv_kernel<<<dim3(8,32,1), 256, 0, stream>>>(sw2,    s2h, s2l, 2048,512);
  wconv_kernel<<<dim3(32,8,E_),256, 0, stream>>>(ew1,    e1h, e1l, 512, 2048);
  wconv_kernel<<<dim3(8,32,E_),256, 0, stream>>>(ew2,    e2h, e2l, 2048,512);

  // 1. xn = LN1(x) -> split planes
  ln_split_kernel<<<dim3(TOK_), 256, 0, stream>>>(x, n1g, n1b, xnh, xnl, 1e-6f);
  // 2. q = xn @ q_w + q_b (f32 out)
  gemm_mfma<GEPI_PLAIN><<<dim3(4,64), 256, 0, stream>>>(xnh,xnl,qwh,qwl,q_b, qsb,nullptr,nullptr, TOK_,512,512, nullptr,nullptr,0);
  // 3. kv = xn @ kv_w + kv_b
  gemm_mfma<GEPI_PLAIN><<<dim3(8,64), 256, 0, stream>>>(xnh,xnl,kvwh,kvwl,kv_b, kvb,nullptr,nullptr, TOK_,512,1024, nullptr,nullptr,0);
  // 4. srg = gelu(xn @ sr_w + sr_b) (f32, pooling source)
  gemm_mfma<GEPI_GELU_F32><<<dim3(4,64), 256, 0, stream>>>(xnh,xnl,srwh,srwl,sr_b, srg,nullptr,nullptr, TOK_,512,512, nullptr,nullptr,0);
  // 5. xp = LN(mean-pool)
  pool_ln_kernel<<<dim3(B_*P_), 256, 0, stream>>>(srg, npg, npb, xp);
  // 6. kvp = xp @ kv_w + kv_b (tiny, f32 vector path)
  gemm_f32<EPI_PLAIN><<<dim3(8,1), 256, 0, stream>>>(xp, kv_w, kv_b, kvp, B_*P_, 512, 1024, nullptr, nullptr, 0);
  // 7. kP = rope(kvp[:, :D])
  kp_rope_kernel<<<dim3(B_*P_), 512, 0, stream>>>(kvp, kpb);
  // 8. qs post
  qs_post_kernel<<<dim3(B_*N_*H_/4), 256, 0, stream>>>(qsb, temp);
  // 9. kln
  k_post_kernel<<<dim3(B_*N_*H_/4), 256, 0, stream>>>(kvb, kln);
  // 10. attention -> split attn_out (8-lane groups)
  attn_kernel<<<dim3(B_*H_*N_/32), 256, 0, stream>>>(qsb, kln, kvb, kpb, kvp, atth, attl);
  // 11. out = x + attn_out @ proj_w + proj_b
  gemm_mfma<GEPI_RESID><<<dim3(4,64), 256, 0, stream>>>(atth,attl,pjwh,pjwl,proj_b, out,nullptr,nullptr, TOK_,512,512, x,nullptr,0);
  // 12. xn2 = LN2(out) -> split planes (reuse xn region)
  ln_split_kernel<<<dim3(TOK_), 256, 0, stream>>>(out, n2g, n2b, xnh, xnl, 1e-6f);
  // 13-14. router + stats
  zero_stats_kernel<<<dim3(1), 64, 0, stream>>>(stats);
  router_kernel<<<dim3(TOK_/4), 256, 0, stream>>>(xnh, xnl, rw, rb, gates, stats);
  // 15. MoE (hid planes reuse qsb/kvb/kln region)
  gemm_mfma<GEPI_GELU_HILO><<<dim3(16,64), 256, 0, stream>>>(xnh,xnl,s1h,s1l,sb1, nullptr,hidh,hidl, TOK_,512,HID_, nullptr,nullptr,0);
  gemm_mfma<GEPI_ACC><<<dim3(4,64), 256, 0, stream>>>(hidh,hidl,s2h,s2l,sb2, out,nullptr,nullptr, TOK_,HID_,512, nullptr,nullptr,0);
  for(int e=0;e<E_;++e){
    gemm_mfma<GEPI_GELU_HILO><<<dim3(16,64), 256, 0, stream>>>(xnh,xnl, e1h+(size_t)e*512*2048, e1l+(size_t)e*512*2048, eb1+(size_t)e*HID_, nullptr,hidh,hidl, TOK_,512,HID_, nullptr,nullptr,0);
    gemm_mfma<GEPI_ACC><<<dim3(4,64), 256, 0, stream>>>(hidh,hidl, e2h+(size_t)e*2048*512, e2l+(size_t)e*2048*512, eb2+(size_t)e*D_, out,nullptr,nullptr, TOK_,HID_,512, nullptr,gates+e,E_);
  }
  // 16. aux scalar
  aux_kernel<<<dim3(1), 1, 0, stream>>>(stats, out + S);
}

// Round 8
// 945.532 us; speedup vs baseline: 3.7149x; 1.3622x over previous
//
#include <hip/hip_runtime.h>
#include <hip/hip_bf16.h>
#include <math.h>

#define B_ 4
#define N_ 2048
#define D_ 512
#define H_ 8
#define HD_ 64
#define KW_ 9
#define P_ 8
#define E_ 4
#define HID_ 2048
#define TOK_ (B_*N_)   // 8192

typedef __bf16 bf16x8 __attribute__((ext_vector_type(8)));
typedef float  f32x4  __attribute__((ext_vector_type(4)));

static __device__ __forceinline__ float wave_sum(float v){
#pragma unroll
  for(int off=32; off>0; off>>=1) v += __shfl_xor(v, off);
  return v;
}

static __device__ __forceinline__ float gelu_exact(float v){
  return 0.5f * v * (1.f + erff(v * 0.70710678118654752440f));
}

// split f32 into hi+lo bf16 (3-term MFMA gives ~f32 product precision)
static __device__ __forceinline__ void split2(float v, unsigned short& h, unsigned short& l){
  __bf16 bh = (__bf16)v;
  float r = v - (float)bh;
  __bf16 bl = (__bf16)r;
  h = __builtin_bit_cast(unsigned short, bh);
  l = __builtin_bit_cast(unsigned short, bl);
}
static __device__ __forceinline__ float bf2f(unsigned short u){
  return (float)__builtin_bit_cast(__bf16, u);
}
static __device__ __forceinline__ unsigned short f2bf(float v){
  return __builtin_bit_cast(unsigned short, (__bf16)v);
}

// async global->LDS, 16B per lane, LDS dest = wave-uniform base + lane*16
static __device__ __forceinline__ void gload16(const unsigned short* g, unsigned short* l){
  __builtin_amdgcn_global_load_lds(
      (const __attribute__((address_space(1))) unsigned int*)g,
      (__attribute__((address_space(3))) unsigned int*)l, 16, 0, 0);
}

// ---------------- weight convert: W f32 [K][N] -> Wt hi/lo bf16 [N][K] ----------
__global__ __launch_bounds__(256) void wconv_kernel(const float* __restrict__ W,
    unsigned short* __restrict__ Th, unsigned short* __restrict__ Tl, int K, int N)
{
  size_t ms = (size_t)K*N;
  const float* Wb = W + blockIdx.z*ms;
  unsigned short* Thb = Th + blockIdx.z*ms;
  unsigned short* Tlb = Tl + blockIdx.z*ms;
  __shared__ float tile[64][65];
  int n0 = blockIdx.x*64, k0 = blockIdx.y*64;
  int t = threadIdx.x;
  int c4 = (t&15)*4, r = t>>4;
#pragma unroll
  for(int pass=0; pass<4; ++pass){
    int k = r + pass*16;
    float4 v = *(const float4*)(Wb + (size_t)(k0+k)*N + n0 + c4);
    tile[k][c4]=v.x; tile[k][c4+1]=v.y; tile[k][c4+2]=v.z; tile[k][c4+3]=v.w;
  }
  __syncthreads();
#pragma unroll
  for(int pass=0; pass<4; ++pass){
    int n = r + pass*16;
    unsigned short h0,h1,h2,h3,l0,l1,l2,l3;
    split2(tile[c4+0][n], h0, l0);
    split2(tile[c4+1][n], h1, l1);
    split2(tile[c4+2][n], h2, l2);
    split2(tile[c4+3][n], h3, l3);
    *(ushort4*)(Thb + (size_t)(n0+n)*K + k0 + c4) = make_ushort4(h0,h1,h2,h3);
    *(ushort4*)(Tlb + (size_t)(n0+n)*K + k0 + c4) = make_ushort4(l0,l1,l2,l3);
  }
}

// ---------------- split-bf16 MFMA GEMM (front path: q/kv/sr/proj) ----------------
#define GEPI_PLAIN     0
#define GEPI_GELU_F32  1
#define GEPI_RESID     2

template<int EPI>
__global__ __launch_bounds__(256,2) void gemm_mfma(
    const unsigned short* __restrict__ Ah, const unsigned short* __restrict__ Al,
    const unsigned short* __restrict__ Bh, const unsigned short* __restrict__ Bl,
    const float* __restrict__ bias,
    float* __restrict__ out,
    int M, int K, int N,
    const float* __restrict__ resid)
{
  __shared__ unsigned short lds[4][128][64];   // Ah,Al,Bh,Bl tiles; 64 KB
  int tid = threadIdx.x;
  int lane = tid & 63, w = tid >> 6;
  int wm = w >> 1, wn = w & 1;
  // bijective XCD swizzle (all grids here have nwg % 8 == 0)
  int nbx = gridDim.x;
  int nwg = nbx * gridDim.y;
  int orig = blockIdx.y*nbx + blockIdx.x;
  int cpx = nwg >> 3;
  int swz = (orig & 7)*cpx + (orig >> 3);
  int bx = swz % nbx, by = swz / nbx;
  int row0 = by*128, col0 = bx*128;
  int r15 = lane & 15, g = lane >> 4;
  const unsigned short* Pb;
  if      (w==0) Pb = Ah + (size_t)row0*K;
  else if (w==1) Pb = Al + (size_t)row0*K;
  else if (w==2) Pb = Bh + (size_t)col0*K;
  else           Pb = Bl + (size_t)col0*K;
  const unsigned short* Pl = Pb + (size_t)(lane>>3)*K + (lane&7)*8;

  f32x4 acc[4][4];
#pragma unroll
  for(int i=0;i<4;++i)
#pragma unroll
    for(int j=0;j<4;++j) acc[i][j] = (f32x4){0.f,0.f,0.f,0.f};

  for(int k0=0; k0<K; k0+=64){
    __syncthreads();
#pragma unroll
    for(int c=0;c<16;++c){
      gload16(Pl + (size_t)(c*8)*K + k0, &lds[w][c*8][0]);
    }
    __syncthreads();
#pragma unroll
    for(int ks=0; ks<2; ++ks){
      bf16x8 afh[4], afl[4], bfh[4], bfl[4];
#pragma unroll
      for(int mf=0; mf<4; ++mf){
        int row = wm*64 + mf*16 + r15;
        afh[mf] = *(const bf16x8*)&lds[0][row][(ks*4+g)*8];
        afl[mf] = *(const bf16x8*)&lds[1][row][(ks*4+g)*8];
      }
#pragma unroll
      for(int nf=0; nf<4; ++nf){
        int row = wn*64 + nf*16 + r15;
        bfh[nf] = *(const bf16x8*)&lds[2][row][(ks*4+g)*8];
        bfl[nf] = *(const bf16x8*)&lds[3][row][(ks*4+g)*8];
      }
#pragma unroll
      for(int mf=0; mf<4; ++mf)
#pragma unroll
        for(int nf=0; nf<4; ++nf){
          acc[mf][nf] = __builtin_amdgcn_mfma_f32_16x16x32_bf16(afh[mf], bfh[nf], acc[mf][nf], 0,0,0);
          acc[mf][nf] = __builtin_amdgcn_mfma_f32_16x16x32_bf16(afh[mf], bfl[nf], acc[mf][nf], 0,0,0);
          acc[mf][nf] = __builtin_amdgcn_mfma_f32_16x16x32_bf16(afl[mf], bfh[nf], acc[mf][nf], 0,0,0);
        }
    }
  }
#pragma unroll
  for(int mf=0; mf<4; ++mf){
#pragma unroll
    for(int nf=0; nf<4; ++nf){
      int col = col0 + wn*64 + nf*16 + r15;
      float bv = bias[col];
#pragma unroll
      for(int v=0; v<4; ++v){
        int row = row0 + wm*64 + mf*16 + g*4 + v;
        size_t o = (size_t)row*N + col;
        float val = acc[mf][nf][v] + bv;
        if      (EPI == GEPI_GELU_F32){ out[o] = gelu_exact(val); }
        else if (EPI == GEPI_RESID){ out[o] = val + resid[o]; }
        else { out[o] = val; }
      }
    }
  }
}

// ---------------- pure-bf16 MFMA GEMM (MoE path), 32KB LDS, 4+ blocks/CU ---------
#define G2_GELU 0
#define G2_ACC  1

template<int EPI>
__global__ __launch_bounds__(256,4) void gemm_bf16(
    const unsigned short* __restrict__ Ah,
    const unsigned short* __restrict__ Bh,
    const float* __restrict__ bias,
    float* __restrict__ out, unsigned short* __restrict__ outh,
    int M, int K, int N,
    const float* __restrict__ gate, int gstride)
{
  __shared__ unsigned short lds[2][128][64];   // A,B tiles; 32 KB
  int tid = threadIdx.x;
  int lane = tid & 63, w = tid >> 6;
  int wm = w >> 1, wn = w & 1;
  int nbx = gridDim.x;
  int nwg = nbx * gridDim.y;
  int orig = blockIdx.y*nbx + blockIdx.x;
  int cpx = nwg >> 3;
  int swz = (orig & 7)*cpx + (orig >> 3);
  int bx = swz % nbx, by = swz / nbx;
  int row0 = by*128, col0 = bx*128;
  int r15 = lane & 15, g = lane >> 4;
  int plane = w >> 1, half = w & 1;    // wave stages rows [half*64, half*64+64) of plane
  const unsigned short* Pb = (plane==0) ? (Ah + (size_t)(row0+half*64)*K)
                                        : (Bh + (size_t)(col0+half*64)*K);
  const unsigned short* Pl = Pb + (size_t)(lane>>3)*K + (lane&7)*8;

  f32x4 acc[4][4];
#pragma unroll
  for(int i=0;i<4;++i)
#pragma unroll
    for(int j=0;j<4;++j) acc[i][j] = (f32x4){0.f,0.f,0.f,0.f};

  for(int k0=0; k0<K; k0+=64){
    __syncthreads();
#pragma unroll
    for(int c=0;c<8;++c){
      gload16(Pl + (size_t)(c*8)*K + k0, &lds[plane][half*64 + c*8][0]);
    }
    __syncthreads();
#pragma unroll
    for(int ks=0; ks<2; ++ks){
      bf16x8 af[4], bf[4];
#pragma unroll
      for(int mf=0; mf<4; ++mf)
        af[mf] = *(const bf16x8*)&lds[0][wm*64 + mf*16 + r15][(ks*4+g)*8];
#pragma unroll
      for(int nf=0; nf<4; ++nf)
        bf[nf] = *(const bf16x8*)&lds[1][wn*64 + nf*16 + r15][(ks*4+g)*8];
#pragma unroll
      for(int mf=0; mf<4; ++mf)
#pragma unroll
        for(int nf=0; nf<4; ++nf)
          acc[mf][nf] = __builtin_amdgcn_mfma_f32_16x16x32_bf16(af[mf], bf[nf], acc[mf][nf], 0,0,0);
    }
  }
#pragma unroll
  for(int mf=0; mf<4; ++mf){
#pragma unroll
    for(int nf=0; nf<4; ++nf){
      int col = col0 + wn*64 + nf*16 + r15;
      float bv = bias[col];
#pragma unroll
      for(int v=0; v<4; ++v){
        int row = row0 + wm*64 + mf*16 + g*4 + v;
        size_t o = (size_t)row*N + col;
        float val = acc[mf][nf][v] + bv;
        if (EPI == G2_GELU){ outh[o] = f2bf(gelu_exact(val)); }
        else {
          float gv = gate ? gate[(size_t)row*gstride] : 1.f;
          out[o] += gv * val;
        }
      }
    }
  }
}

// ---------------- legacy f32 vector GEMM (only for the tiny 32-row kvp GEMM) -----
#define EPI_PLAIN 0
template<int EPI>
__global__ __launch_bounds__(256) void gemm_f32(
    const float* __restrict__ A, const float* __restrict__ W,
    const float* __restrict__ bias, float* __restrict__ out,
    int M, int Kd, int Nw,
    const float* __restrict__ resid,
    const float* __restrict__ gate, int gstride)
{
  __shared__ __align__(16) float As[16][128];
  __shared__ __align__(16) float Bs[16][128];
  int tid = threadIdx.x;
  int tx = tid & 15, ty = tid >> 4;
  int row0 = blockIdx.y * 128, col0 = blockIdx.x * 128;
  float acc[8][8];
#pragma unroll
  for(int i=0;i<8;++i)
#pragma unroll
    for(int j=0;j<8;++j) acc[i][j]=0.f;

  for(int k0=0; k0<Kd; k0+=16){
#pragma unroll
    for(int i=0;i<2;++i){
      int f4 = tid*2+i;
      int r  = f4 >> 2;
      int kc = (f4 & 3) << 2;
      int gr = row0 + r;
      float4 v = make_float4(0.f,0.f,0.f,0.f);
      if (gr < M) v = *(const float4*)(A + (size_t)gr*Kd + k0 + kc);
      As[kc+0][r]=v.x; As[kc+1][r]=v.y; As[kc+2][r]=v.z; As[kc+3][r]=v.w;
    }
#pragma unroll
    for(int i=0;i<2;++i){
      int f4 = tid*2+i;
      int kr = f4 >> 5;
      int c  = (f4 & 31) << 2;
      *(float4*)&Bs[kr][c] = *(const float4*)(W + (size_t)(k0+kr)*Nw + col0 + c);
    }
    __syncthreads();
#pragma unroll
    for(int kk=0;kk<16;++kk){
      float a[8], b[8];
      float4 a0 = *(const float4*)&As[kk][ty*8];
      float4 a1 = *(const float4*)&As[kk][ty*8+4];
      a[0]=a0.x;a[1]=a0.y;a[2]=a0.z;a[3]=a0.w;
      a[4]=a1.x;a[5]=a1.y;a[6]=a1.z;a[7]=a1.w;
      float4 b0 = *(const float4*)&Bs[kk][tx*8];
      float4 b1 = *(const float4*)&Bs[kk][tx*8+4];
      b[0]=b0.x;b[1]=b0.y;b[2]=b0.z;b[3]=b0.w;
      b[4]=b1.x;b[5]=b1.y;b[6]=b1.z;b[7]=b1.w;
#pragma unroll
      for(int i=0;i<8;++i)
#pragma unroll
        for(int j=0;j<8;++j)
          acc[i][j] = fmaf(a[i], b[j], acc[i][j]);
    }
    __syncthreads();
  }
#pragma unroll
  for(int i=0;i<8;++i){
    int gr = row0 + ty*8 + i;
    if (gr >= M) continue;
    size_t rb = (size_t)gr * Nw;
#pragma unroll
    for(int j=0;j<8;++j){
      int gc = col0 + tx*8 + j;
      out[rb+gc] = acc[i][j] + bias[gc];
    }
  }
}

// ---------------- LayerNorm -> split bf16 planes ---------------------------------
__global__ __launch_bounds__(256) void ln_split_kernel(const float* __restrict__ in,
    const float* __restrict__ g, const float* __restrict__ b,
    unsigned short* __restrict__ outh, unsigned short* __restrict__ outl, float eps)
{
  int r = blockIdx.x;
  int tid = threadIdx.x;
  const float* rp = in + (size_t)r * D_;
  float2 v = *(const float2*)(rp + tid*2);
  float s = v.x + v.y;
  float q = v.x*v.x + v.y*v.y;
  s = wave_sum(s); q = wave_sum(q);
  __shared__ float ss[4], qq[4];
  int wid = tid >> 6, lane = tid & 63;
  if(lane==0){ ss[wid]=s; qq[wid]=q; }
  __syncthreads();
  float S = ss[0]+ss[1]+ss[2]+ss[3];
  float Q = qq[0]+qq[1]+qq[2]+qq[3];
  float mean = S * (1.f/D_);
  float var = Q * (1.f/D_) - mean*mean;
  float rstd = rsqrtf(var + eps);
  int d = tid*2;
  float o0 = (v.x-mean)*rstd*g[d]   + b[d];
  float o1 = (v.y-mean)*rstd*g[d+1] + b[d+1];
  unsigned short h0,l0,h1,l1;
  split2(o0,h0,l0); split2(o1,h1,l1);
  *(ushort2*)(outh + (size_t)r*D_ + d) = make_ushort2(h0,h1);
  *(ushort2*)(outl + (size_t)r*D_ + d) = make_ushort2(l0,l1);
}

// ---------------- q post (f32, in place) -----------------------------------------
__global__ __launch_bounds__(256) void qs_post_kernel(float* __restrict__ q,
                                                      const float* __restrict__ temp)
{
  int tid = threadIdx.x;
  int gid = blockIdx.x*4 + (tid>>6);
  int dd  = tid & 63;
  int h = gid % H_;
  int n = (gid / H_) % N_;
  int b = gid / (H_*N_);
  size_t idx = ((size_t)(b*N_+n))*D_ + h*HD_ + dd;
  float v = q[idx];
  float ss = wave_sum(v*v);
  v = v / fmaxf(sqrtf(ss), 1e-12f);
  float t = temp[h];
  float sp = log1pf(expf(t));
  v *= sp * 2.77258872223978124f;
  float partner = __shfl_xor(v, 32);
  int i = dd & 31;
  float inv = 1.f / powf(10000.f, (float)i * (1.f/32.f));
  float ang = (float)n * inv;
  float s, c; sincosf(ang, &s, &c);
  q[idx] = (dd < 32) ? fmaf(v, c, -partner*s) : fmaf(partner, s, v*c);
}

// ---------------- k post ---------------------------------------------------------
__global__ __launch_bounds__(256) void k_post_kernel(const float* __restrict__ kvb,
                                                     float* __restrict__ kln)
{
  int tid = threadIdx.x;
  int gid = blockIdx.x*4 + (tid>>6);
  int dd  = tid & 63;
  int h = gid % H_;
  int n = (gid / H_) % N_;
  int b = gid / (H_*N_);
  float v = kvb[((size_t)(b*N_+n))*(2*D_) + h*HD_ + dd];
  float partner = __shfl_xor(v, 32);
  int i = dd & 31;
  float inv = 1.f / powf(10000.f, (float)i * (1.f/32.f));
  float ang = (float)n * inv;
  float s, c; sincosf(ang, &s, &c);
  float r = (dd < 32) ? fmaf(v, c, -partner*s) : fmaf(partner, s, v*c);
  float ss = wave_sum(r*r);
  r = r / fmaxf(sqrtf(ss), 1e-12f);
  kln[((size_t)(b*N_+n))*D_ + h*HD_ + dd] = r;
}

// ---------------- pooled path ----------------------------------------------------
__global__ __launch_bounds__(256) void pool_ln_kernel(const float* __restrict__ src,
    const float* __restrict__ g, const float* __restrict__ b, float* __restrict__ xp)
{
  int bp = blockIdx.x;
  int bb = bp / P_, p = bp % P_;
  int tid = threadIdx.x;
  const float* base = src + ((size_t)(bb*N_ + p*(N_/P_)))*D_;
  float a0=0.f, a1=0.f;
  for(int i=0;i<N_/P_;++i){
    a0 += base[(size_t)i*D_ + tid];
    a1 += base[(size_t)i*D_ + tid + 256];
  }
  a0 *= (1.f/(N_/P_)); a1 *= (1.f/(N_/P_));
  float s = a0+a1, q = a0*a0+a1*a1;
  s = wave_sum(s); q = wave_sum(q);
  __shared__ float ss[4], qq[4];
  int wid = tid>>6, lane = tid&63;
  if(lane==0){ ss[wid]=s; qq[wid]=q; }
  __syncthreads();
  float S = ss[0]+ss[1]+ss[2]+ss[3];
  float Q = qq[0]+qq[1]+qq[2]+qq[3];
  float mean = S*(1.f/D_);
  float var  = Q*(1.f/D_) - mean*mean;
  float rstd = rsqrtf(var + 1e-5f);
  xp[(size_t)bp*D_ + tid]       = (a0-mean)*rstd*g[tid]     + b[tid];
  xp[(size_t)bp*D_ + tid + 256] = (a1-mean)*rstd*g[tid+256] + b[tid+256];
}

// ---------------- kP rope --------------------------------------------------------
__global__ __launch_bounds__(512) void kp_rope_kernel(const float* __restrict__ kvp,
                                                      float* __restrict__ kpb)
{
  int bp = blockIdx.x;
  int d  = threadIdx.x;
  int dd = d & 63;
  int p  = bp % P_;
  float v = kvp[(size_t)bp*(2*D_) + d];
  float partner = __shfl_xor(v, 32);
  int i = dd & 31;
  float inv = 1.f / powf(10000.f, (float)i * (1.f/32.f));
  float ang = (float)p * inv;
  float s, c; sincosf(ang, &s, &c);
  kpb[(size_t)bp*D_ + d] = (dd < 32) ? fmaf(v, c, -partner*s) : fmaf(partner, s, v*c);
}

// ---------------- attention: 8-lane groups, lane holds 8 of 64 d-values ----------
static __device__ __forceinline__ float dot4(float4 a, float4 b){
  return fmaf(a.x,b.x, fmaf(a.y,b.y, fmaf(a.z,b.z, a.w*b.w)));
}

__global__ __launch_bounds__(256) void attn_kernel(
    const float* __restrict__ qs, const float* __restrict__ kln,
    const float* __restrict__ kvb, const float* __restrict__ kpb,
    const float* __restrict__ kvp,
    unsigned short* __restrict__ outh, unsigned short* __restrict__ outl)
{
  int tid = threadIdx.x;
  int gid = blockIdx.x*32 + (tid>>3);  // (b*N+n)*H + h
  int l   = tid & 7;
  int d0  = l*8;
  int h = gid % H_;
  int n = (gid / H_) % N_;
  int b = gid / (H_*N_);
  size_t tok = (size_t)(b*N_+n);
  const float* qp = qs + tok*D_ + h*HD_ + d0;
  float4 qa = *(const float4*)qp;
  float4 qb = *(const float4*)(qp+4);
  float lg[KW_+P_];
#pragma unroll
  for(int j=0;j<KW_;++j){
    int np  = n - KW_/2 + j;
    int npc = min(max(np,0), N_-1);
    const float* kp = kln + ((size_t)(b*N_+npc))*D_ + h*HD_ + d0;
    float4 ka = *(const float4*)kp;
    float4 kb = *(const float4*)(kp+4);
    float d = dot4(qa,ka) + dot4(qb,kb);
#pragma unroll
    for(int off=1; off<8; off<<=1) d += __shfl_xor(d, off);
    lg[j] = (np>=0 && np<N_) ? d : -3.0e38f;
  }
#pragma unroll
  for(int p=0;p<P_;++p){
    const float* kp = kpb + ((size_t)(b*P_+p))*D_ + h*HD_ + d0;
    float4 ka = *(const float4*)kp;
    float4 kb = *(const float4*)(kp+4);
    float d = dot4(qa,ka) + dot4(qb,kb);
#pragma unroll
    for(int off=1; off<8; off<<=1) d += __shfl_xor(d, off);
    lg[KW_+p] = d;
  }
  float m = lg[0];
#pragma unroll
  for(int j=1;j<KW_+P_;++j) m = fmaxf(m, lg[j]);
  float a[KW_+P_]; float sum = 0.f;
#pragma unroll
  for(int j=0;j<KW_+P_;++j){ a[j] = expf(lg[j]-m); sum += a[j]; }
  float inv = 1.f / sum;
  float4 oa = make_float4(0.f,0.f,0.f,0.f);
  float4 ob = make_float4(0.f,0.f,0.f,0.f);
#pragma unroll
  for(int j=0;j<KW_;++j){
    int npc = min(max(n - KW_/2 + j, 0), N_-1);
    const float* vp = kvb + ((size_t)(b*N_+npc))*(2*D_) + D_ + h*HD_ + d0;
    float4 va = *(const float4*)vp;
    float4 vb = *(const float4*)(vp+4);
    oa.x=fmaf(a[j],va.x,oa.x); oa.y=fmaf(a[j],va.y,oa.y); oa.z=fmaf(a[j],va.z,oa.z); oa.w=fmaf(a[j],va.w,oa.w);
    ob.x=fmaf(a[j],vb.x,ob.x); ob.y=fmaf(a[j],vb.y,ob.y); ob.z=fmaf(a[j],vb.z,ob.z); ob.w=fmaf(a[j],vb.w,ob.w);
  }
#pragma unroll
  for(int p=0;p<P_;++p){
    float w = a[KW_+p];
    const float* vp = kvp + ((size_t)(b*P_+p))*(2*D_) + D_ + h*HD_ + d0;
    float4 va = *(const float4*)vp;
    float4 vb = *(const float4*)(vp+4);
    oa.x=fmaf(w,va.x,oa.x); oa.y=fmaf(w,va.y,oa.y); oa.z=fmaf(w,va.z,oa.z); oa.w=fmaf(w,va.w,oa.w);
    ob.x=fmaf(w,vb.x,ob.x); ob.y=fmaf(w,vb.y,ob.y); ob.z=fmaf(w,vb.z,ob.z); ob.w=fmaf(w,vb.w,ob.w);
  }
  unsigned short h0,h1,h2,h3,l0,l1,l2,l3;
  size_t ob_ = tok*D_ + h*HD_ + d0;
  split2(oa.x*inv,h0,l0); split2(oa.y*inv,h1,l1); split2(oa.z*inv,h2,l2); split2(oa.w*inv,h3,l3);
  *(ushort4*)(outh + ob_)   = make_ushort4(h0,h1,h2,h3);
  *(ushort4*)(outl + ob_)   = make_ushort4(l0,l1,l2,l3);
  split2(ob.x*inv,h0,l0); split2(ob.y*inv,h1,l1); split2(ob.z*inv,h2,l2); split2(ob.w*inv,h3,l3);
  *(ushort4*)(outh + ob_+4) = make_ushort4(h0,h1,h2,h3);
  *(ushort4*)(outl + ob_+4) = make_ushort4(l0,l1,l2,l3);
}

// ---------------- router + stats (reads split xn2) -------------------------------
__global__ void zero_stats_kernel(float* stats){
  if(threadIdx.x < 16) stats[threadIdx.x] = 0.f;
}

__global__ __launch_bounds__(256) void router_kernel(
    const unsigned short* __restrict__ xh, const unsigned short* __restrict__ xl,
    const float* __restrict__ rw, const float* __restrict__ rb,
    float* __restrict__ gates, float* __restrict__ stats)
{
  int tid = threadIdx.x;
  int wid = tid>>6, lane = tid&63;
  int t = blockIdx.x*4 + wid;
  float a0=0.f,a1=0.f,a2=0.f,a3=0.f;
  for(int k=lane;k<D_;k+=64){
    float xv = bf2f(xh[(size_t)t*D_+k]) + bf2f(xl[(size_t)t*D_+k]);
    float4 w = *(const float4*)(rw + (size_t)k*E_);
    a0 = fmaf(xv,w.x,a0); a1 = fmaf(xv,w.y,a1);
    a2 = fmaf(xv,w.z,a2); a3 = fmaf(xv,w.w,a3);
  }
  a0=wave_sum(a0); a1=wave_sum(a1); a2=wave_sum(a2); a3=wave_sum(a3);
  __shared__ float sg[4][E_], sc[4][E_];
  if(lane==0){
    float lg[E_] = {a0+rb[0], a1+rb[1], a2+rb[2], a3+rb[3]};
    float m = fmaxf(fmaxf(lg[0],lg[1]), fmaxf(lg[2],lg[3]));
    float e[E_]; float sum=0.f;
#pragma unroll
    for(int k=0;k<E_;++k){ e[k]=expf(lg[k]-m); sum+=e[k]; }
    float inv = 1.f/sum;
    int am = 0; float bv = lg[0];
#pragma unroll
    for(int k=1;k<E_;++k) if(lg[k] > bv){ bv = lg[k]; am = k; }
#pragma unroll
    for(int k=0;k<E_;++k){
      float gk = e[k]*inv;
      gates[(size_t)t*E_ + k] = gk;
      sg[wid][k] = gk;
      sc[wid][k] = (k==am) ? 1.f : 0.f;
    }
  }
  __syncthreads();
  if(tid < E_){
    atomicAdd(stats + tid,      sc[0][tid]+sc[1][tid]+sc[2][tid]+sc[3][tid]);
    atomicAdd(stats + E_ + tid, sg[0][tid]+sg[1][tid]+sg[2][tid]+sg[3][tid]);
  }
}

__global__ void aux_kernel(const float* __restrict__ stats, float* __restrict__ outp){
  float acc = 0.f;
  const float inv = 1.f / (float)TOK_;
#pragma unroll
  for(int e=0;e<E_;++e) acc += (stats[e]*inv) * (stats[E_+e]*inv);
  *outp = 0.01f * (float)E_ * acc;
}

// =================================================================================
extern "C" void kernel_launch(void* const* d_in, const int* in_sizes, int n_in,
                              void* d_out, int out_size, void* d_ws, size_t ws_size,
                              hipStream_t stream)
{
  const float* x      = (const float*)d_in[0];
  const float* temp   = (const float*)d_in[1];
  const float* q_w    = (const float*)d_in[2];
  const float* q_b    = (const float*)d_in[3];
  const float* kv_w   = (const float*)d_in[4];
  const float* kv_b   = (const float*)d_in[5];
  const float* proj_w = (const float*)d_in[6];
  const float* proj_b = (const float*)d_in[7];
  const float* n1g    = (const float*)d_in[8];
  const float* n1b    = (const float*)d_in[9];
  const float* n2g    = (const float*)d_in[10];
  const float* n2b    = (const float*)d_in[11];
  const float* sr_w   = (const float*)d_in[12];
  const float* sr_b   = (const float*)d_in[13];
  const float* npg    = (const float*)d_in[14];
  const float* npb    = (const float*)d_in[15];
  const float* rw     = (const float*)d_in[16];
  const float* rb     = (const float*)d_in[17];
  const float* ew1    = (const float*)d_in[18];
  const float* eb1    = (const float*)d_in[19];
  const float* ew2    = (const float*)d_in[20];
  const float* eb2    = (const float*)d_in[21];
  const float* sw1    = (const float*)d_in[22];
  const float* sb1    = (const float*)d_in[23];
  const float* sw2    = (const float*)d_in[24];
  const float* sb2    = (const float*)d_in[25];

  float* out = (float*)d_out;
  const size_t S = (size_t)TOK_ * D_;          // 4,194,304
  char* base = (char*)d_ws;
  size_t off = 0;
  auto aus = [&](size_t n)->unsigned short*{ unsigned short* p=(unsigned short*)(base+off); off += n*2; return p; };
  auto af  = [&](size_t n)->float*{ float* p=(float*)(base+off); off += n*4; return p; };

  // persistent weight planes (transposed [N][K])
  unsigned short *qwh = aus(512*512),  *qwl = aus(512*512);
  unsigned short *kvwh= aus(512*1024), *kvwl= aus(512*1024);
  unsigned short *srwh= aus(512*512),  *srwl= aus(512*512);
  unsigned short *pjwh= aus(512*512),  *pjwl= aus(512*512);
  unsigned short *s1h = aus(512*2048), *s1l = aus(512*2048);
  unsigned short *s2h = aus(2048*512), *s2l = aus(2048*512);
  unsigned short *e1h = aus((size_t)E_*512*2048), *e1l = aus((size_t)E_*512*2048);
  unsigned short *e2h = aus((size_t)E_*2048*512), *e2l = aus((size_t)E_*2048*512);
  // xn planes (reused later as xn2 planes)
  unsigned short *xnh = aus(S), *xnl = aus(S);
  // f32 region: qsb + kvb + kln (reused later as hid bf16 plane, 4S elems)
  float* qsb = af(S);
  float* kvb = af(2*S);
  float* kln = af(S);
  unsigned short* hidh = (unsigned short*)qsb;   // 4S ushorts fit in qsb+kvb
  // srg f32 (reused later as attn_out planes)
  float* srg = af(S);
  unsigned short* atth = (unsigned short*)srg;
  unsigned short* attl = atth + S;
  // small tail
  float* xp    = af((size_t)B_*P_*D_);
  float* kvp   = af((size_t)B_*P_*2*D_);
  float* kpb   = af((size_t)B_*P_*D_);
  float* gates = af((size_t)TOK_*E_);
  float* stats = af(16);

  // 0. weight convert+transpose+split
  wconv_kernel<<<dim3(8,8,1),  256, 0, stream>>>(q_w,    qwh, qwl, 512, 512);
  wconv_kernel<<<dim3(16,8,1), 256, 0, stream>>>(kv_w,   kvwh,kvwl,512, 1024);
  wconv_kernel<<<dim3(8,8,1),  256, 0, stream>>>(sr_w,   srwh,srwl,512, 512);
  wconv_kernel<<<dim3(8,8,1),  256, 0, stream>>>(proj_w, pjwh,pjwl,512, 512);
  wconv_kernel<<<dim3(32,8,1), 256, 0, stream>>>(sw1,    s1h, s1l, 512, 2048);
  wconv_kernel<<<dim3(8,32,1), 256, 0, stream>>>(sw2,    s2h, s2l, 2048,512);
  wconv_kernel<<<dim3(32,8,E_),256, 0, stream>>>(ew1,    e1h, e1l, 512, 2048);
  wconv_kernel<<<dim3(8,32,E_),256, 0, stream>>>(ew2,    e2h, e2l, 2048,512);

  // 1. xn = LN1(x) -> split planes
  ln_split_kernel<<<dim3(TOK_), 256, 0, stream>>>(x, n1g, n1b, xnh, xnl, 1e-6f);
  // 2. q = xn @ q_w + q_b (f32 out)
  gemm_mfma<GEPI_PLAIN><<<dim3(4,64), 256, 0, stream>>>(xnh,xnl,qwh,qwl,q_b, qsb, TOK_,512,512, nullptr);
  // 3. kv = xn @ kv_w + kv_b
  gemm_mfma<GEPI_PLAIN><<<dim3(8,64), 256, 0, stream>>>(xnh,xnl,kvwh,kvwl,kv_b, kvb, TOK_,512,1024, nullptr);
  // 4. srg = gelu(xn @ sr_w + sr_b) (f32, pooling source)
  gemm_mfma<GEPI_GELU_F32><<<dim3(4,64), 256, 0, stream>>>(xnh,xnl,srwh,srwl,sr_b, srg, TOK_,512,512, nullptr);
  // 5. xp = LN(mean-pool)
  pool_ln_kernel<<<dim3(B_*P_), 256, 0, stream>>>(srg, npg, npb, xp);
  // 6. kvp = xp @ kv_w + kv_b (tiny, f32 vector path)
  gemm_f32<EPI_PLAIN><<<dim3(8,1), 256, 0, stream>>>(xp, kv_w, kv_b, kvp, B_*P_, 512, 1024, nullptr, nullptr, 0);
  // 7. kP = rope(kvp[:, :D])
  kp_rope_kernel<<<dim3(B_*P_), 512, 0, stream>>>(kvp, kpb);
  // 8. qs post
  qs_post_kernel<<<dim3(B_*N_*H_/4), 256, 0, stream>>>(qsb, temp);
  // 9. kln
  k_post_kernel<<<dim3(B_*N_*H_/4), 256, 0, stream>>>(kvb, kln);
  // 10. attention -> split attn_out (8-lane groups)
  attn_kernel<<<dim3(B_*H_*N_/32), 256, 0, stream>>>(qsb, kln, kvb, kpb, kvp, atth, attl);
  // 11. out = x + attn_out @ proj_w + proj_b
  gemm_mfma<GEPI_RESID><<<dim3(4,64), 256, 0, stream>>>(atth,attl,pjwh,pjwl,proj_b, out, TOK_,512,512, x);
  // 12. xn2 = LN2(out) -> split planes (reuse xn region)
  ln_split_kernel<<<dim3(TOK_), 256, 0, stream>>>(out, n2g, n2b, xnh, xnl, 1e-6f);
  // 13-14. router + stats
  zero_stats_kernel<<<dim3(1), 64, 0, stream>>>(stats);
  router_kernel<<<dim3(TOK_/4), 256, 0, stream>>>(xnh, xnl, rw, rb, gates, stats);
  // 15. MoE, pure bf16 (error analysis: ~1e-3 std vs 0.0156 floor)
  gemm_bf16<G2_GELU><<<dim3(16,64), 256, 0, stream>>>(xnh, s1h, sb1, nullptr, hidh, TOK_,512,HID_, nullptr,0);
  gemm_bf16<G2_ACC ><<<dim3(4,64),  256, 0, stream>>>(hidh, s2h, sb2, out, nullptr, TOK_,HID_,512, nullptr,0);
  for(int e=0;e<E_;++e){
    gemm_bf16<G2_GELU><<<dim3(16,64), 256, 0, stream>>>(xnh, e1h+(size_t)e*512*2048, eb1+(size_t)e*HID_, nullptr, hidh, TOK_,512,HID_, nullptr,0);
    gemm_bf16<G2_ACC ><<<dim3(4,64),  256, 0, stream>>>(hidh, e2h+(size_t)e*2048*512, eb2+(size_t)e*D_, out, nullptr, TOK_,HID_,512, gates+e,E_);
  }
  // 16. aux scalar
  aux_kernel<<<dim3(1), 1, 0, stream>>>(stats, out + S);
}

// Round 9
// 937.894 us; speedup vs baseline: 3.7451x; 1.0081x over previous
//
#include <hip/hip_runtime.h>
#include <hip/hip_bf16.h>
#include <math.h>

#define B_ 4
#define N_ 2048
#define D_ 512
#define H_ 8
#define HD_ 64
#define KW_ 9
#define P_ 8
#define E_ 4
#define HID_ 2048
#define TOK_ (B_*N_)   // 8192

typedef __bf16 bf16x8 __attribute__((ext_vector_type(8)));
typedef float  f32x4  __attribute__((ext_vector_type(4)));

#define LOG2_10000_OVER_32 0.41524101186092034f

static __device__ __forceinline__ float wave_sum(float v){
#pragma unroll
  for(int off=32; off>0; off>>=1) v += __shfl_xor(v, off);
  return v;
}

static __device__ __forceinline__ float gelu_exact(float v){
  return 0.5f * v * (1.f + erff(v * 0.70710678118654752440f));
}

// split f32 into hi+lo bf16 (3-term MFMA gives ~f32 product precision)
static __device__ __forceinline__ void split2(float v, unsigned short& h, unsigned short& l){
  __bf16 bh = (__bf16)v;
  float r = v - (float)bh;
  __bf16 bl = (__bf16)r;
  h = __builtin_bit_cast(unsigned short, bh);
  l = __builtin_bit_cast(unsigned short, bl);
}
static __device__ __forceinline__ float bf2f(unsigned short u){
  return (float)__builtin_bit_cast(__bf16, u);
}
static __device__ __forceinline__ unsigned short f2bf(float v){
  return __builtin_bit_cast(unsigned short, (__bf16)v);
}

// async global->LDS, 16B per lane, LDS dest = wave-uniform base + lane*16
static __device__ __forceinline__ void gload16(const unsigned short* g, unsigned short* l){
  __builtin_amdgcn_global_load_lds(
      (const __attribute__((address_space(1))) unsigned int*)g,
      (__attribute__((address_space(3))) unsigned int*)l, 16, 0, 0);
}

// ---------------- weight convert: W f32 [K][N] -> Wt hi/lo bf16 [N][K] ----------
__global__ __launch_bounds__(256) void wconv_kernel(const float* __restrict__ W,
    unsigned short* __restrict__ Th, unsigned short* __restrict__ Tl, int K, int N)
{
  size_t ms = (size_t)K*N;
  const float* Wb = W + blockIdx.z*ms;
  unsigned short* Thb = Th + blockIdx.z*ms;
  unsigned short* Tlb = Tl + blockIdx.z*ms;
  __shared__ float tile[64][65];
  int n0 = blockIdx.x*64, k0 = blockIdx.y*64;
  int t = threadIdx.x;
  int c4 = (t&15)*4, r = t>>4;
#pragma unroll
  for(int pass=0; pass<4; ++pass){
    int k = r + pass*16;
    float4 v = *(const float4*)(Wb + (size_t)(k0+k)*N + n0 + c4);
    tile[k][c4]=v.x; tile[k][c4+1]=v.y; tile[k][c4+2]=v.z; tile[k][c4+3]=v.w;
  }
  __syncthreads();
#pragma unroll
  for(int pass=0; pass<4; ++pass){
    int n = r + pass*16;
    unsigned short h0,h1,h2,h3,l0,l1,l2,l3;
    split2(tile[c4+0][n], h0, l0);
    split2(tile[c4+1][n], h1, l1);
    split2(tile[c4+2][n], h2, l2);
    split2(tile[c4+3][n], h3, l3);
    *(ushort4*)(Thb + (size_t)(n0+n)*K + k0 + c4) = make_ushort4(h0,h1,h2,h3);
    *(ushort4*)(Tlb + (size_t)(n0+n)*K + k0 + c4) = make_ushort4(l0,l1,l2,l3);
  }
}

// ---------------- split-bf16 MFMA GEMM (front path), BK=32, 32KB LDS -------------
#define GEPI_PLAIN     0
#define GEPI_GELU_F32  1
#define GEPI_RESID     2

template<int EPI>
__global__ __launch_bounds__(256,4) void gemm_mfma(
    const unsigned short* __restrict__ Ah, const unsigned short* __restrict__ Al,
    const unsigned short* __restrict__ Bh, const unsigned short* __restrict__ Bl,
    const float* __restrict__ bias,
    float* __restrict__ out,
    int M, int K, int N,
    const float* __restrict__ resid)
{
  __shared__ unsigned short lds[4][128][32];   // Ah,Al,Bh,Bl tiles; 32 KB
  int tid = threadIdx.x;
  int lane = tid & 63, w = tid >> 6;
  int wm = w >> 1, wn = w & 1;
  // bijective XCD swizzle (all grids here have nwg % 8 == 0)
  int nbx = gridDim.x;
  int nwg = nbx * gridDim.y;
  int orig = blockIdx.y*nbx + blockIdx.x;
  int cpx = nwg >> 3;
  int swz = (orig & 7)*cpx + (orig >> 3);
  int bx = swz % nbx, by = swz / nbx;
  int row0 = by*128, col0 = bx*128;
  int r15 = lane & 15, g = lane >> 4;
  const unsigned short* Pb;
  if      (w==0) Pb = Ah + (size_t)row0*K;
  else if (w==1) Pb = Al + (size_t)row0*K;
  else if (w==2) Pb = Bh + (size_t)col0*K;
  else           Pb = Bl + (size_t)col0*K;
  const unsigned short* Pl = Pb + (size_t)(lane>>2)*K + (lane&3)*8;

  f32x4 acc[4][4];
#pragma unroll
  for(int i=0;i<4;++i)
#pragma unroll
    for(int j=0;j<4;++j) acc[i][j] = (f32x4){0.f,0.f,0.f,0.f};

  for(int k0=0; k0<K; k0+=32){
    __syncthreads();
#pragma unroll
    for(int c=0;c<8;++c){
      gload16(Pl + (size_t)(c*16)*K + k0, &lds[w][c*16][0]);
    }
    __syncthreads();
    bf16x8 afh[4], afl[4], bfh[4], bfl[4];
#pragma unroll
    for(int mf=0; mf<4; ++mf){
      int row = wm*64 + mf*16 + r15;
      afh[mf] = *(const bf16x8*)&lds[0][row][g*8];
      afl[mf] = *(const bf16x8*)&lds[1][row][g*8];
    }
#pragma unroll
    for(int nf=0; nf<4; ++nf){
      int row = wn*64 + nf*16 + r15;
      bfh[nf] = *(const bf16x8*)&lds[2][row][g*8];
      bfl[nf] = *(const bf16x8*)&lds[3][row][g*8];
    }
#pragma unroll
    for(int mf=0; mf<4; ++mf)
#pragma unroll
      for(int nf=0; nf<4; ++nf){
        acc[mf][nf] = __builtin_amdgcn_mfma_f32_16x16x32_bf16(afh[mf], bfh[nf], acc[mf][nf], 0,0,0);
        acc[mf][nf] = __builtin_amdgcn_mfma_f32_16x16x32_bf16(afh[mf], bfl[nf], acc[mf][nf], 0,0,0);
        acc[mf][nf] = __builtin_amdgcn_mfma_f32_16x16x32_bf16(afl[mf], bfh[nf], acc[mf][nf], 0,0,0);
      }
  }
#pragma unroll
  for(int mf=0; mf<4; ++mf){
#pragma unroll
    for(int nf=0; nf<4; ++nf){
      int col = col0 + wn*64 + nf*16 + r15;
      float bv = bias[col];
#pragma unroll
      for(int v=0; v<4; ++v){
        int row = row0 + wm*64 + mf*16 + g*4 + v;
        size_t o = (size_t)row*N + col;
        float val = acc[mf][nf][v] + bv;
        if      (EPI == GEPI_GELU_F32){ out[o] = gelu_exact(val); }
        else if (EPI == GEPI_RESID){ out[o] = val + resid[o]; }
        else { out[o] = val; }
      }
    }
  }
}

// ---------------- pure-bf16 MFMA GEMM (MoE path), 32KB LDS, 4+ blocks/CU ---------
#define G2_GELU 0
#define G2_ACC  1

template<int EPI>
__global__ __launch_bounds__(256,4) void gemm_bf16(
    const unsigned short* __restrict__ Ah,
    const unsigned short* __restrict__ Bh,
    const float* __restrict__ bias,
    float* __restrict__ out, unsigned short* __restrict__ outh,
    int M, int K, int N,
    const float* __restrict__ gate, int gstride)
{
  __shared__ unsigned short lds[2][128][64];   // A,B tiles; 32 KB
  int tid = threadIdx.x;
  int lane = tid & 63, w = tid >> 6;
  int wm = w >> 1, wn = w & 1;
  int nbx = gridDim.x;
  int nwg = nbx * gridDim.y;
  int orig = blockIdx.y*nbx + blockIdx.x;
  int cpx = nwg >> 3;
  int swz = (orig & 7)*cpx + (orig >> 3);
  int bx = swz % nbx, by = swz / nbx;
  int row0 = by*128, col0 = bx*128;
  int r15 = lane & 15, g = lane >> 4;
  int plane = w >> 1, half = w & 1;    // wave stages rows [half*64, half*64+64) of plane
  const unsigned short* Pb = (plane==0) ? (Ah + (size_t)(row0+half*64)*K)
                                        : (Bh + (size_t)(col0+half*64)*K);
  const unsigned short* Pl = Pb + (size_t)(lane>>3)*K + (lane&7)*8;

  f32x4 acc[4][4];
#pragma unroll
  for(int i=0;i<4;++i)
#pragma unroll
    for(int j=0;j<4;++j) acc[i][j] = (f32x4){0.f,0.f,0.f,0.f};

  for(int k0=0; k0<K; k0+=64){
    __syncthreads();
#pragma unroll
    for(int c=0;c<8;++c){
      gload16(Pl + (size_t)(c*8)*K + k0, &lds[plane][half*64 + c*8][0]);
    }
    __syncthreads();
#pragma unroll
    for(int ks=0; ks<2; ++ks){
      bf16x8 af[4], bf[4];
#pragma unroll
      for(int mf=0; mf<4; ++mf)
        af[mf] = *(const bf16x8*)&lds[0][wm*64 + mf*16 + r15][(ks*4+g)*8];
#pragma unroll
      for(int nf=0; nf<4; ++nf)
        bf[nf] = *(const bf16x8*)&lds[1][wn*64 + nf*16 + r15][(ks*4+g)*8];
#pragma unroll
      for(int mf=0; mf<4; ++mf)
#pragma unroll
        for(int nf=0; nf<4; ++nf)
          acc[mf][nf] = __builtin_amdgcn_mfma_f32_16x16x32_bf16(af[mf], bf[nf], acc[mf][nf], 0,0,0);
    }
  }
#pragma unroll
  for(int mf=0; mf<4; ++mf){
#pragma unroll
    for(int nf=0; nf<4; ++nf){
      int col = col0 + wn*64 + nf*16 + r15;
      float bv = bias[col];
#pragma unroll
      for(int v=0; v<4; ++v){
        int row = row0 + wm*64 + mf*16 + g*4 + v;
        size_t o = (size_t)row*N + col;
        float val = acc[mf][nf][v] + bv;
        if (EPI == G2_GELU){ outh[o] = f2bf(gelu_exact(val)); }
        else {
          float gv = gate ? gate[(size_t)row*gstride] : 1.f;
          out[o] += gv * val;
        }
      }
    }
  }
}

// ---------------- dedicated tiny GEMM: kvp = xp(32x512) @ kv_w(512x1024) + b -----
__global__ __launch_bounds__(256) void kvp_small_kernel(
    const float* __restrict__ xp, const float* __restrict__ W,
    const float* __restrict__ bias, float* __restrict__ out)
{
  __shared__ float xr[512];
  int row = blockIdx.y;            // 0..31
  int col = blockIdx.x*256 + threadIdx.x;
  float2 v = *(const float2*)(xp + (size_t)row*512 + threadIdx.x*2);
  xr[threadIdx.x*2]   = v.x;
  xr[threadIdx.x*2+1] = v.y;
  __syncthreads();
  float acc = 0.f;
#pragma unroll 8
  for(int k=0;k<512;++k)
    acc = fmaf(xr[k], W[(size_t)k*1024 + col], acc);
  out[(size_t)row*1024 + col] = acc + bias[col];
}

// ---------------- LayerNorm -> split bf16 planes ---------------------------------
__global__ __launch_bounds__(256) void ln_split_kernel(const float* __restrict__ in,
    const float* __restrict__ g, const float* __restrict__ b,
    unsigned short* __restrict__ outh, unsigned short* __restrict__ outl, float eps)
{
  int r = blockIdx.x;
  int tid = threadIdx.x;
  const float* rp = in + (size_t)r * D_;
  float2 v = *(const float2*)(rp + tid*2);
  float s = v.x + v.y;
  float q = v.x*v.x + v.y*v.y;
  s = wave_sum(s); q = wave_sum(q);
  __shared__ float ss[4], qq[4];
  int wid = tid >> 6, lane = tid & 63;
  if(lane==0){ ss[wid]=s; qq[wid]=q; }
  __syncthreads();
  float S = ss[0]+ss[1]+ss[2]+ss[3];
  float Q = qq[0]+qq[1]+qq[2]+qq[3];
  float mean = S * (1.f/D_);
  float var = Q * (1.f/D_) - mean*mean;
  float rstd = rsqrtf(var + eps);
  int d = tid*2;
  float o0 = (v.x-mean)*rstd*g[d]   + b[d];
  float o1 = (v.y-mean)*rstd*g[d+1] + b[d+1];
  unsigned short h0,l0,h1,l1;
  split2(o0,h0,l0); split2(o1,h1,l1);
  *(ushort2*)(outh + (size_t)r*D_ + d) = make_ushort2(h0,h1);
  *(ushort2*)(outl + (size_t)r*D_ + d) = make_ushort2(l0,l1);
}

// ---------------- q post (f32, in place) -----------------------------------------
__global__ __launch_bounds__(256) void qs_post_kernel(float* __restrict__ q,
                                                      const float* __restrict__ temp)
{
  int tid = threadIdx.x;
  int gid = blockIdx.x*4 + (tid>>6);
  int dd  = tid & 63;
  int h = gid % H_;
  int n = (gid / H_) % N_;
  int b = gid / (H_*N_);
  size_t idx = ((size_t)(b*N_+n))*D_ + h*HD_ + dd;
  float v = q[idx];
  float ss = wave_sum(v*v);
  v = v / fmaxf(sqrtf(ss), 1e-12f);
  float t = temp[h];
  float sp = log1pf(expf(t));
  v *= sp * 2.77258872223978124f;
  float partner = __shfl_xor(v, 32);
  int i = dd & 31;
  float inv = exp2f(-(float)i * LOG2_10000_OVER_32);
  float ang = (float)n * inv;
  float s, c; sincosf(ang, &s, &c);
  q[idx] = (dd < 32) ? fmaf(v, c, -partner*s) : fmaf(partner, s, v*c);
}

// ---------------- k post ---------------------------------------------------------
__global__ __launch_bounds__(256) void k_post_kernel(const float* __restrict__ kvb,
                                                     float* __restrict__ kln)
{
  int tid = threadIdx.x;
  int gid = blockIdx.x*4 + (tid>>6);
  int dd  = tid & 63;
  int h = gid % H_;
  int n = (gid / H_) % N_;
  int b = gid / (H_*N_);
  float v = kvb[((size_t)(b*N_+n))*(2*D_) + h*HD_ + dd];
  float partner = __shfl_xor(v, 32);
  int i = dd & 31;
  float inv = exp2f(-(float)i * LOG2_10000_OVER_32);
  float ang = (float)n * inv;
  float s, c; sincosf(ang, &s, &c);
  float r = (dd < 32) ? fmaf(v, c, -partner*s) : fmaf(partner, s, v*c);
  float ss = wave_sum(r*r);
  r = r / fmaxf(sqrtf(ss), 1e-12f);
  kln[((size_t)(b*N_+n))*D_ + h*HD_ + dd] = r;
}

// ---------------- pooled path ----------------------------------------------------
__global__ __launch_bounds__(256) void pool_ln_kernel(const float* __restrict__ src,
    const float* __restrict__ g, const float* __restrict__ b, float* __restrict__ xp)
{
  int bp = blockIdx.x;
  int bb = bp / P_, p = bp % P_;
  int tid = threadIdx.x;
  const float* base = src + ((size_t)(bb*N_ + p*(N_/P_)))*D_;
  float a0=0.f, a1=0.f;
  for(int i=0;i<N_/P_;++i){
    a0 += base[(size_t)i*D_ + tid];
    a1 += base[(size_t)i*D_ + tid + 256];
  }
  a0 *= (1.f/(N_/P_)); a1 *= (1.f/(N_/P_));
  float s = a0+a1, q = a0*a0+a1*a1;
  s = wave_sum(s); q = wave_sum(q);
  __shared__ float ss[4], qq[4];
  int wid = tid>>6, lane = tid&63;
  if(lane==0){ ss[wid]=s; qq[wid]=q; }
  __syncthreads();
  float S = ss[0]+ss[1]+ss[2]+ss[3];
  float Q = qq[0]+qq[1]+qq[2]+qq[3];
  float mean = S*(1.f/D_);
  float var  = Q*(1.f/D_) - mean*mean;
  float rstd = rsqrtf(var + 1e-5f);
  xp[(size_t)bp*D_ + tid]       = (a0-mean)*rstd*g[tid]     + b[tid];
  xp[(size_t)bp*D_ + tid + 256] = (a1-mean)*rstd*g[tid+256] + b[tid+256];
}

// ---------------- kP rope --------------------------------------------------------
__global__ __launch_bounds__(512) void kp_rope_kernel(const float* __restrict__ kvp,
                                                      float* __restrict__ kpb)
{
  int bp = blockIdx.x;
  int d  = threadIdx.x;
  int dd = d & 63;
  int p  = bp % P_;
  float v = kvp[(size_t)bp*(2*D_) + d];
  float partner = __shfl_xor(v, 32);
  int i = dd & 31;
  float inv = exp2f(-(float)i * LOG2_10000_OVER_32);
  float ang = (float)p * inv;
  float s, c; sincosf(ang, &s, &c);
  kpb[(size_t)bp*D_ + d] = (dd < 32) ? fmaf(v, c, -partner*s) : fmaf(partner, s, v*c);
}

// ---------------- attention: 8-lane groups, lane holds 8 of 64 d-values ----------
static __device__ __forceinline__ float dot4(float4 a, float4 b){
  return fmaf(a.x,b.x, fmaf(a.y,b.y, fmaf(a.z,b.z, a.w*b.w)));
}

__global__ __launch_bounds__(256) void attn_kernel(
    const float* __restrict__ qs, const float* __restrict__ kln,
    const float* __restrict__ kvb, const float* __restrict__ kpb,
    const float* __restrict__ kvp,
    unsigned short* __restrict__ outh, unsigned short* __restrict__ outl)
{
  int tid = threadIdx.x;
  int gid = blockIdx.x*32 + (tid>>3);  // (b*N+n)*H + h
  int l   = tid & 7;
  int d0  = l*8;
  int h = gid % H_;
  int n = (gid / H_) % N_;
  int b = gid / (H_*N_);
  size_t tok = (size_t)(b*N_+n);
  const float* qp = qs + tok*D_ + h*HD_ + d0;
  float4 qa = *(const float4*)qp;
  float4 qb = *(const float4*)(qp+4);
  float lg[KW_+P_];
#pragma unroll
  for(int j=0;j<KW_;++j){
    int np  = n - KW_/2 + j;
    int npc = min(max(np,0), N_-1);
    const float* kp = kln + ((size_t)(b*N_+npc))*D_ + h*HD_ + d0;
    float4 ka = *(const float4*)kp;
    float4 kb = *(const float4*)(kp+4);
    float d = dot4(qa,ka) + dot4(qb,kb);
#pragma unroll
    for(int off=1; off<8; off<<=1) d += __shfl_xor(d, off);
    lg[j] = (np>=0 && np<N_) ? d : -3.0e38f;
  }
#pragma unroll
  for(int p=0;p<P_;++p){
    const float* kp = kpb + ((size_t)(b*P_+p))*D_ + h*HD_ + d0;
    float4 ka = *(const float4*)kp;
    float4 kb = *(const float4*)(kp+4);
    float d = dot4(qa,ka) + dot4(qb,kb);
#pragma unroll
    for(int off=1; off<8; off<<=1) d += __shfl_xor(d, off);
    lg[KW_+p] = d;
  }
  float m = lg[0];
#pragma unroll
  for(int j=1;j<KW_+P_;++j) m = fmaxf(m, lg[j]);
  float a[KW_+P_]; float sum = 0.f;
#pragma unroll
  for(int j=0;j<KW_+P_;++j){ a[j] = expf(lg[j]-m); sum += a[j]; }
  float inv = 1.f / sum;
  float4 oa = make_float4(0.f,0.f,0.f,0.f);
  float4 ob = make_float4(0.f,0.f,0.f,0.f);
#pragma unroll
  for(int j=0;j<KW_;++j){
    int npc = min(max(n - KW_/2 + j, 0), N_-1);
    const float* vp = kvb + ((size_t)(b*N_+npc))*(2*D_) + D_ + h*HD_ + d0;
    float4 va = *(const float4*)vp;
    float4 vb = *(const float4*)(vp+4);
    oa.x=fmaf(a[j],va.x,oa.x); oa.y=fmaf(a[j],va.y,oa.y); oa.z=fmaf(a[j],va.z,oa.z); oa.w=fmaf(a[j],va.w,oa.w);
    ob.x=fmaf(a[j],vb.x,ob.x); ob.y=fmaf(a[j],vb.y,ob.y); ob.z=fmaf(a[j],vb.z,ob.z); ob.w=fmaf(a[j],vb.w,ob.w);
  }
#pragma unroll
  for(int p=0;p<P_;++p){
    float w = a[KW_+p];
    const float* vp = kvp + ((size_t)(b*P_+p))*(2*D_) + D_ + h*HD_ + d0;
    float4 va = *(const float4*)vp;
    float4 vb = *(const float4*)(vp+4);
    oa.x=fmaf(w,va.x,oa.x); oa.y=fmaf(w,va.y,oa.y); oa.z=fmaf(w,va.z,oa.z); oa.w=fmaf(w,va.w,oa.w);
    ob.x=fmaf(w,vb.x,ob.x); ob.y=fmaf(w,vb.y,ob.y); ob.z=fmaf(w,vb.z,ob.z); ob.w=fmaf(w,vb.w,ob.w);
  }
  unsigned short h0,h1,h2,h3,l0,l1,l2,l3;
  size_t ob_ = tok*D_ + h*HD_ + d0;
  split2(oa.x*inv,h0,l0); split2(oa.y*inv,h1,l1); split2(oa.z*inv,h2,l2); split2(oa.w*inv,h3,l3);
  *(ushort4*)(outh + ob_)   = make_ushort4(h0,h1,h2,h3);
  *(ushort4*)(outl + ob_)   = make_ushort4(l0,l1,l2,l3);
  split2(ob.x*inv,h0,l0); split2(ob.y*inv,h1,l1); split2(ob.z*inv,h2,l2); split2(ob.w*inv,h3,l3);
  *(ushort4*)(outh + ob_+4) = make_ushort4(h0,h1,h2,h3);
  *(ushort4*)(outl + ob_+4) = make_ushort4(l0,l1,l2,l3);
}

// ---------------- router + stats (reads split xn2) -------------------------------
__global__ void zero_stats_kernel(float* stats){
  if(threadIdx.x < 16) stats[threadIdx.x] = 0.f;
}

__global__ __launch_bounds__(256) void router_kernel(
    const unsigned short* __restrict__ xh, const unsigned short* __restrict__ xl,
    const float* __restrict__ rw, const float* __restrict__ rb,
    float* __restrict__ gates, float* __restrict__ stats)
{
  int tid = threadIdx.x;
  int wid = tid>>6, lane = tid&63;
  int t = blockIdx.x*4 + wid;
  float a0=0.f,a1=0.f,a2=0.f,a3=0.f;
  for(int k=lane;k<D_;k+=64){
    float xv = bf2f(xh[(size_t)t*D_+k]) + bf2f(xl[(size_t)t*D_+k]);
    float4 w = *(const float4*)(rw + (size_t)k*E_);
    a0 = fmaf(xv,w.x,a0); a1 = fmaf(xv,w.y,a1);
    a2 = fmaf(xv,w.z,a2); a3 = fmaf(xv,w.w,a3);
  }
  a0=wave_sum(a0); a1=wave_sum(a1); a2=wave_sum(a2); a3=wave_sum(a3);
  __shared__ float sg[4][E_], sc[4][E_];
  if(lane==0){
    float lg[E_] = {a0+rb[0], a1+rb[1], a2+rb[2], a3+rb[3]};
    float m = fmaxf(fmaxf(lg[0],lg[1]), fmaxf(lg[2],lg[3]));
    float e[E_]; float sum=0.f;
#pragma unroll
    for(int k=0;k<E_;++k){ e[k]=expf(lg[k]-m); sum+=e[k]; }
    float inv = 1.f/sum;
    int am = 0; float bv = lg[0];
#pragma unroll
    for(int k=1;k<E_;++k) if(lg[k] > bv){ bv = lg[k]; am = k; }
#pragma unroll
    for(int k=0;k<E_;++k){
      float gk = e[k]*inv;
      gates[(size_t)t*E_ + k] = gk;
      sg[wid][k] = gk;
      sc[wid][k] = (k==am) ? 1.f : 0.f;
    }
  }
  __syncthreads();
  if(tid < E_){
    atomicAdd(stats + tid,      sc[0][tid]+sc[1][tid]+sc[2][tid]+sc[3][tid]);
    atomicAdd(stats + E_ + tid, sg[0][tid]+sg[1][tid]+sg[2][tid]+sg[3][tid]);
  }
}

__global__ void aux_kernel(const float* __restrict__ stats, float* __restrict__ outp){
  float acc = 0.f;
  const float inv = 1.f / (float)TOK_;
#pragma unroll
  for(int e=0;e<E_;++e) acc += (stats[e]*inv) * (stats[E_+e]*inv);
  *outp = 0.01f * (float)E_ * acc;
}

// =================================================================================
extern "C" void kernel_launch(void* const* d_in, const int* in_sizes, int n_in,
                              void* d_out, int out_size, void* d_ws, size_t ws_size,
                              hipStream_t stream)
{
  const float* x      = (const float*)d_in[0];
  const float* temp   = (const float*)d_in[1];
  const float* q_w    = (const float*)d_in[2];
  const float* q_b    = (const float*)d_in[3];
  const float* kv_w   = (const float*)d_in[4];
  const float* kv_b   = (const float*)d_in[5];
  const float* proj_w = (const float*)d_in[6];
  const float* proj_b = (const float*)d_in[7];
  const float* n1g    = (const float*)d_in[8];
  const float* n1b    = (const float*)d_in[9];
  const float* n2g    = (const float*)d_in[10];
  const float* n2b    = (const float*)d_in[11];
  const float* sr_w   = (const float*)d_in[12];
  const float* sr_b   = (const float*)d_in[13];
  const float* npg    = (const float*)d_in[14];
  const float* npb    = (const float*)d_in[15];
  const float* rw     = (const float*)d_in[16];
  const float* rb     = (const float*)d_in[17];
  const float* ew1    = (const float*)d_in[18];
  const float* eb1    = (const float*)d_in[19];
  const float* ew2    = (const float*)d_in[20];
  const float* eb2    = (const float*)d_in[21];
  const float* sw1    = (const float*)d_in[22];
  const float* sb1    = (const float*)d_in[23];
  const float* sw2    = (const float*)d_in[24];
  const float* sb2    = (const float*)d_in[25];

  float* out = (float*)d_out;
  const size_t S = (size_t)TOK_ * D_;          // 4,194,304
  char* base = (char*)d_ws;
  size_t off = 0;
  auto aus = [&](size_t n)->unsigned short*{ unsigned short* p=(unsigned short*)(base+off); off += n*2; return p; };
  auto af  = [&](size_t n)->float*{ float* p=(float*)(base+off); off += n*4; return p; };

  // persistent weight planes (transposed [N][K])
  unsigned short *qwh = aus(512*512),  *qwl = aus(512*512);
  unsigned short *kvwh= aus(512*1024), *kvwl= aus(512*1024);
  unsigned short *srwh= aus(512*512),  *srwl= aus(512*512);
  unsigned short *pjwh= aus(512*512),  *pjwl= aus(512*512);
  unsigned short *s1h = aus(512*2048), *s1l = aus(512*2048);
  unsigned short *s2h = aus(2048*512), *s2l = aus(2048*512);
  unsigned short *e1h = aus((size_t)E_*512*2048), *e1l = aus((size_t)E_*512*2048);
  unsigned short *e2h = aus((size_t)E_*2048*512), *e2l = aus((size_t)E_*2048*512);
  // xn planes (reused later as xn2 planes)
  unsigned short *xnh = aus(S), *xnl = aus(S);
  // f32 region: qsb + kvb + kln (reused later as hid bf16 plane, 4S elems)
  float* qsb = af(S);
  float* kvb = af(2*S);
  float* kln = af(S);
  unsigned short* hidh = (unsigned short*)qsb;   // 4S ushorts fit in qsb+kvb
  // srg f32 (reused later as attn_out planes)
  float* srg = af(S);
  unsigned short* atth = (unsigned short*)srg;
  unsigned short* attl = atth + S;
  // small tail
  float* xp    = af((size_t)B_*P_*D_);
  float* kvp   = af((size_t)B_*P_*2*D_);
  float* kpb   = af((size_t)B_*P_*D_);
  float* gates = af((size_t)TOK_*E_);
  float* stats = af(16);

  // 0. weight convert+transpose+split
  wconv_kernel<<<dim3(8,8,1),  256, 0, stream>>>(q_w,    qwh, qwl, 512, 512);
  wconv_kernel<<<dim3(16,8,1), 256, 0, stream>>>(kv_w,   kvwh,kvwl,512, 1024);
  wconv_kernel<<<dim3(8,8,1),  256, 0, stream>>>(sr_w,   srwh,srwl,512, 512);
  wconv_kernel<<<dim3(8,8,1),  256, 0, stream>>>(proj_w, pjwh,pjwl,512, 512);
  wconv_kernel<<<dim3(32,8,1), 256, 0, stream>>>(sw1,    s1h, s1l, 512, 2048);
  wconv_kernel<<<dim3(8,32,1), 256, 0, stream>>>(sw2,    s2h, s2l, 2048,512);
  wconv_kernel<<<dim3(32,8,E_),256, 0, stream>>>(ew1,    e1h, e1l, 512, 2048);
  wconv_kernel<<<dim3(8,32,E_),256, 0, stream>>>(ew2,    e2h, e2l, 2048,512);

  // 1. xn = LN1(x) -> split planes
  ln_split_kernel<<<dim3(TOK_), 256, 0, stream>>>(x, n1g, n1b, xnh, xnl, 1e-6f);
  // 2. q = xn @ q_w + q_b (f32 out)
  gemm_mfma<GEPI_PLAIN><<<dim3(4,64), 256, 0, stream>>>(xnh,xnl,qwh,qwl,q_b, qsb, TOK_,512,512, nullptr);
  // 3. kv = xn @ kv_w + kv_b
  gemm_mfma<GEPI_PLAIN><<<dim3(8,64), 256, 0, stream>>>(xnh,xnl,kvwh,kvwl,kv_b, kvb, TOK_,512,1024, nullptr);
  // 4. srg = gelu(xn @ sr_w + sr_b) (f32, pooling source)
  gemm_mfma<GEPI_GELU_F32><<<dim3(4,64), 256, 0, stream>>>(xnh,xnl,srwh,srwl,sr_b, srg, TOK_,512,512, nullptr);
  // 5. xp = LN(mean-pool)
  pool_ln_kernel<<<dim3(B_*P_), 256, 0, stream>>>(srg, npg, npb, xp);
  // 6. kvp = xp @ kv_w + kv_b (dedicated small-M kernel)
  kvp_small_kernel<<<dim3(4,32), 256, 0, stream>>>(xp, kv_w, kv_b, kvp);
  // 7. kP = rope(kvp[:, :D])
  kp_rope_kernel<<<dim3(B_*P_), 512, 0, stream>>>(kvp, kpb);
  // 8. qs post
  qs_post_kernel<<<dim3(B_*N_*H_/4), 256, 0, stream>>>(qsb, temp);
  // 9. kln
  k_post_kernel<<<dim3(B_*N_*H_/4), 256, 0, stream>>>(kvb, kln);
  // 10. attention -> split attn_out (8-lane groups)
  attn_kernel<<<dim3(B_*H_*N_/32), 256, 0, stream>>>(qsb, kln, kvb, kpb, kvp, atth, attl);
  // 11. out = x + attn_out @ proj_w + proj_b
  gemm_mfma<GEPI_RESID><<<dim3(4,64), 256, 0, stream>>>(atth,attl,pjwh,pjwl,proj_b, out, TOK_,512,512, x);
  // 12. xn2 = LN2(out) -> split planes (reuse xn region)
  ln_split_kernel<<<dim3(TOK_), 256, 0, stream>>>(out, n2g, n2b, xnh, xnl, 1e-6f);
  // 13-14. router + stats
  zero_stats_kernel<<<dim3(1), 64, 0, stream>>>(stats);
  router_kernel<<<dim3(TOK_/4), 256, 0, stream>>>(xnh, xnl, rw, rb, gates, stats);
  // 15. MoE, pure bf16
  gemm_bf16<G2_GELU><<<dim3(16,64), 256, 0, stream>>>(xnh, s1h, sb1, nullptr, hidh, TOK_,512,HID_, nullptr,0);
  gemm_bf16<G2_ACC ><<<dim3(4,64),  256, 0, stream>>>(hidh, s2h, sb2, out, nullptr, TOK_,HID_,512, nullptr,0);
  for(int e=0;e<E_;++e){
    gemm_bf16<G2_GELU><<<dim3(16,64), 256, 0, stream>>>(xnh, e1h+(size_t)e*512*2048, eb1+(size_t)e*HID_, nullptr, hidh, TOK_,512,HID_, nullptr,0);
    gemm_bf16<G2_ACC ><<<dim3(4,64),  256, 0, stream>>>(hidh, e2h+(size_t)e*2048*512, eb2+(size_t)e*D_, out, nullptr, TOK_,HID_,512, gates+e,E_);
  }
  // 16. aux scalar
  aux_kernel<<<dim3(1), 1, 0, stream>>>(stats, out + S);
}

// Round 12
// 764.839 us; speedup vs baseline: 4.5925x; 1.2263x over previous
//
#include <hip/hip_runtime.h>
#include <hip/hip_bf16.h>
#include <math.h>

#define B_ 4
#define N_ 2048
#define D_ 512
#define H_ 8
#define HD_ 64
#define KW_ 9
#define P_ 8
#define E_ 4
#define HID_ 2048
#define TOK_ (B_*N_)   // 8192

typedef __bf16 bf16x8 __attribute__((ext_vector_type(8)));
typedef float  f32x4  __attribute__((ext_vector_type(4)));

#define LOG2_10000_OVER_32 0.41524101186092034f

static __device__ __forceinline__ float wave_sum(float v){
#pragma unroll
  for(int off=32; off>0; off>>=1) v += __shfl_xor(v, off);
  return v;
}

static __device__ __forceinline__ float gelu_exact(float v){
  return 0.5f * v * (1.f + erff(v * 0.70710678118654752440f));
}

// split f32 into hi+lo bf16 (3-term MFMA gives ~f32 product precision)
static __device__ __forceinline__ void split2(float v, unsigned short& h, unsigned short& l){
  __bf16 bh = (__bf16)v;
  float r = v - (float)bh;
  __bf16 bl = (__bf16)r;
  h = __builtin_bit_cast(unsigned short, bh);
  l = __builtin_bit_cast(unsigned short, bl);
}
static __device__ __forceinline__ float bf2f(unsigned short u){
  return (float)__builtin_bit_cast(__bf16, u);
}
static __device__ __forceinline__ unsigned short f2bf(float v){
  return __builtin_bit_cast(unsigned short, (__bf16)v);
}

// async global->LDS, 16B per lane, LDS dest = wave-uniform base + lane*16
static __device__ __forceinline__ void gload16(const unsigned short* g, unsigned short* l){
  __builtin_amdgcn_global_load_lds(
      (const __attribute__((address_space(1))) unsigned int*)g,
      (__attribute__((address_space(3))) unsigned int*)l, 16, 0, 0);
}

// ---------------- weight convert: W f32 [K][N] -> Wt hi/lo bf16 [N][K] ----------
__global__ __launch_bounds__(256) void wconv_kernel(const float* __restrict__ W,
    unsigned short* __restrict__ Th, unsigned short* __restrict__ Tl, int K, int N)
{
  size_t ms = (size_t)K*N;
  const float* Wb = W + blockIdx.z*ms;
  unsigned short* Thb = Th + blockIdx.z*ms;
  unsigned short* Tlb = Tl + blockIdx.z*ms;
  __shared__ float tile[64][65];
  int n0 = blockIdx.x*64, k0 = blockIdx.y*64;
  int t = threadIdx.x;
  int c4 = (t&15)*4, r = t>>4;
#pragma unroll
  for(int pass=0; pass<4; ++pass){
    int k = r + pass*16;
    float4 v = *(const float4*)(Wb + (size_t)(k0+k)*N + n0 + c4);
    tile[k][c4]=v.x; tile[k][c4+1]=v.y; tile[k][c4+2]=v.z; tile[k][c4+3]=v.w;
  }
  __syncthreads();
#pragma unroll
  for(int pass=0; pass<4; ++pass){
    int n = r + pass*16;
    unsigned short h0,h1,h2,h3,l0,l1,l2,l3;
    split2(tile[c4+0][n], h0, l0);
    split2(tile[c4+1][n], h1, l1);
    split2(tile[c4+2][n], h2, l2);
    split2(tile[c4+3][n], h3, l3);
    *(ushort4*)(Thb + (size_t)(n0+n)*K + k0 + c4) = make_ushort4(h0,h1,h2,h3);
    *(ushort4*)(Tlb + (size_t)(n0+n)*K + k0 + c4) = make_ushort4(l0,l1,l2,l3);
  }
}

// ---------------- fused QKVSR split-bf16 GEMM: A(8192x512) @ Wf(512x2048) --------
// Wf = [q_w | kv_w | sr_w] transposed planes. Segment epilogue per 128-col tile.
__global__ __launch_bounds__(256,4) void gemm_qkvsr(
    const unsigned short* __restrict__ Ah, const unsigned short* __restrict__ Al,
    const unsigned short* __restrict__ Bh, const unsigned short* __restrict__ Bl,
    const float* __restrict__ q_b, const float* __restrict__ kv_b, const float* __restrict__ sr_b,
    float* __restrict__ qsb, float* __restrict__ kvb, float* __restrict__ srg,
    int M, int K)
{
  __shared__ unsigned short lds[4][128][32];   // 32 KB
  int tid = threadIdx.x;
  int lane = tid & 63, w = tid >> 6;
  int wm = w >> 1, wn = w & 1;
  int nbx = gridDim.x;                          // 16
  int nwg = nbx * gridDim.y;                    // 1024
  int orig = blockIdx.y*nbx + blockIdx.x;
  int cpx = nwg >> 3;
  int swz = (orig & 7)*cpx + (orig >> 3);
  int bx = swz % nbx, by = swz / nbx;
  int row0 = by*128, col0 = bx*128;
  int r15 = lane & 15, g = lane >> 4;
  const unsigned short* Pb;
  if      (w==0) Pb = Ah + (size_t)row0*K;
  else if (w==1) Pb = Al + (size_t)row0*K;
  else if (w==2) Pb = Bh + (size_t)col0*K;
  else           Pb = Bl + (size_t)col0*K;
  const unsigned short* Pl = Pb + (size_t)(lane>>2)*K + (lane&3)*8;

  f32x4 acc[4][4];
#pragma unroll
  for(int i=0;i<4;++i)
#pragma unroll
    for(int j=0;j<4;++j) acc[i][j] = (f32x4){0.f,0.f,0.f,0.f};

  for(int k0=0; k0<K; k0+=32){
    __syncthreads();
#pragma unroll
    for(int c=0;c<8;++c){
      gload16(Pl + (size_t)(c*16)*K + k0, &lds[w][c*16][0]);
    }
    __syncthreads();
    bf16x8 afh[4], afl[4], bfh[4], bfl[4];
#pragma unroll
    for(int mf=0; mf<4; ++mf){
      int row = wm*64 + mf*16 + r15;
      afh[mf] = *(const bf16x8*)&lds[0][row][g*8];
      afl[mf] = *(const bf16x8*)&lds[1][row][g*8];
    }
#pragma unroll
    for(int nf=0; nf<4; ++nf){
      int row = wn*64 + nf*16 + r15;
      bfh[nf] = *(const bf16x8*)&lds[2][row][g*8];
      bfl[nf] = *(const bf16x8*)&lds[3][row][g*8];
    }
#pragma unroll
    for(int mf=0; mf<4; ++mf)
#pragma unroll
      for(int nf=0; nf<4; ++nf){
        acc[mf][nf] = __builtin_amdgcn_mfma_f32_16x16x32_bf16(afh[mf], bfh[nf], acc[mf][nf], 0,0,0);
        acc[mf][nf] = __builtin_amdgcn_mfma_f32_16x16x32_bf16(afh[mf], bfl[nf], acc[mf][nf], 0,0,0);
        acc[mf][nf] = __builtin_amdgcn_mfma_f32_16x16x32_bf16(afl[mf], bfh[nf], acc[mf][nf], 0,0,0);
      }
  }
  // segment select (block-uniform)
  float* optr; const float* bptr; int nstride, cbase; bool dog;
  if (col0 < 512)      { optr=qsb; bptr=q_b;  nstride=512;  cbase=0;    dog=false; }
  else if (col0 < 1536){ optr=kvb; bptr=kv_b; nstride=1024; cbase=512;  dog=false; }
  else                 { optr=srg; bptr=sr_b; nstride=512;  cbase=1536; dog=true;  }
#pragma unroll
  for(int mf=0; mf<4; ++mf){
#pragma unroll
    for(int nf=0; nf<4; ++nf){
      int colr = col0 - cbase + wn*64 + nf*16 + r15;
      float bv = bptr[colr];
#pragma unroll
      for(int v=0; v<4; ++v){
        int row = row0 + wm*64 + mf*16 + g*4 + v;
        float val = acc[mf][nf][v] + bv;
        optr[(size_t)row*nstride + colr] = dog ? gelu_exact(val) : val;
      }
    }
  }
}

// ---------------- split-bf16 MFMA GEMM (proj), BK=32, 32KB LDS -------------------
#define GEPI_PLAIN     0
#define GEPI_GELU_F32  1
#define GEPI_RESID     2

template<int EPI>
__global__ __launch_bounds__(256,4) void gemm_mfma(
    const unsigned short* __restrict__ Ah, const unsigned short* __restrict__ Al,
    const unsigned short* __restrict__ Bh, const unsigned short* __restrict__ Bl,
    const float* __restrict__ bias,
    float* __restrict__ out,
    int M, int K, int N,
    const float* __restrict__ resid)
{
  __shared__ unsigned short lds[4][128][32];   // 32 KB
  int tid = threadIdx.x;
  int lane = tid & 63, w = tid >> 6;
  int wm = w >> 1, wn = w & 1;
  int nbx = gridDim.x;
  int nwg = nbx * gridDim.y;
  int orig = blockIdx.y*nbx + blockIdx.x;
  int cpx = nwg >> 3;
  int swz = (orig & 7)*cpx + (orig >> 3);
  int bx = swz % nbx, by = swz / nbx;
  int row0 = by*128, col0 = bx*128;
  int r15 = lane & 15, g = lane >> 4;
  const unsigned short* Pb;
  if      (w==0) Pb = Ah + (size_t)row0*K;
  else if (w==1) Pb = Al + (size_t)row0*K;
  else if (w==2) Pb = Bh + (size_t)col0*K;
  else           Pb = Bl + (size_t)col0*K;
  const unsigned short* Pl = Pb + (size_t)(lane>>2)*K + (lane&3)*8;

  f32x4 acc[4][4];
#pragma unroll
  for(int i=0;i<4;++i)
#pragma unroll
    for(int j=0;j<4;++j) acc[i][j] = (f32x4){0.f,0.f,0.f,0.f};

  for(int k0=0; k0<K; k0+=32){
    __syncthreads();
#pragma unroll
    for(int c=0;c<8;++c){
      gload16(Pl + (size_t)(c*16)*K + k0, &lds[w][c*16][0]);
    }
    __syncthreads();
    bf16x8 afh[4], afl[4], bfh[4], bfl[4];
#pragma unroll
    for(int mf=0; mf<4; ++mf){
      int row = wm*64 + mf*16 + r15;
      afh[mf] = *(const bf16x8*)&lds[0][row][g*8];
      afl[mf] = *(const bf16x8*)&lds[1][row][g*8];
    }
#pragma unroll
    for(int nf=0; nf<4; ++nf){
      int row = wn*64 + nf*16 + r15;
      bfh[nf] = *(const bf16x8*)&lds[2][row][g*8];
      bfl[nf] = *(const bf16x8*)&lds[3][row][g*8];
    }
#pragma unroll
    for(int mf=0; mf<4; ++mf)
#pragma unroll
      for(int nf=0; nf<4; ++nf){
        acc[mf][nf] = __builtin_amdgcn_mfma_f32_16x16x32_bf16(afh[mf], bfh[nf], acc[mf][nf], 0,0,0);
        acc[mf][nf] = __builtin_amdgcn_mfma_f32_16x16x32_bf16(afh[mf], bfl[nf], acc[mf][nf], 0,0,0);
        acc[mf][nf] = __builtin_amdgcn_mfma_f32_16x16x32_bf16(afl[mf], bfh[nf], acc[mf][nf], 0,0,0);
      }
  }
#pragma unroll
  for(int mf=0; mf<4; ++mf){
#pragma unroll
    for(int nf=0; nf<4; ++nf){
      int col = col0 + wn*64 + nf*16 + r15;
      float bv = bias[col];
#pragma unroll
      for(int v=0; v<4; ++v){
        int row = row0 + wm*64 + mf*16 + g*4 + v;
        size_t o = (size_t)row*N + col;
        float val = acc[mf][nf][v] + bv;
        if      (EPI == GEPI_GELU_F32){ out[o] = gelu_exact(val); }
        else if (EPI == GEPI_RESID){ out[o] = val + resid[o]; }
        else { out[o] = val; }
      }
    }
  }
}

// ---------------- pure-bf16 MFMA GEMM 128x128 (MoE GEMM1), 32KB LDS --------------
#define G2_GELU 0
#define G2_ACC  1

template<int EPI>
__global__ __launch_bounds__(256,4) void gemm_bf16(
    const unsigned short* __restrict__ Ah,
    const unsigned short* __restrict__ Bh,
    const float* __restrict__ bias,
    float* __restrict__ out, unsigned short* __restrict__ outh,
    int M, int K, int N,
    const float* __restrict__ gate, int gstride)
{
  __shared__ unsigned short lds[2][128][64];   // 32 KB
  int tid = threadIdx.x;
  int lane = tid & 63, w = tid >> 6;
  int wm = w >> 1, wn = w & 1;
  int nbx = gridDim.x;
  int nwg = nbx * gridDim.y;
  int orig = blockIdx.y*nbx + blockIdx.x;
  int cpx = nwg >> 3;
  int swz = (orig & 7)*cpx + (orig >> 3);
  int bx = swz % nbx, by = swz / nbx;
  int row0 = by*128, col0 = bx*128;
  int r15 = lane & 15, g = lane >> 4;
  int plane = w >> 1, half = w & 1;
  const unsigned short* Pb = (plane==0) ? (Ah + (size_t)(row0+half*64)*K)
                                        : (Bh + (size_t)(col0+half*64)*K);
  const unsigned short* Pl = Pb + (size_t)(lane>>3)*K + (lane&7)*8;

  f32x4 acc[4][4];
#pragma unroll
  for(int i=0;i<4;++i)
#pragma unroll
    for(int j=0;j<4;++j) acc[i][j] = (f32x4){0.f,0.f,0.f,0.f};

  for(int k0=0; k0<K; k0+=64){
    __syncthreads();
#pragma unroll
    for(int c=0;c<8;++c){
      gload16(Pl + (size_t)(c*8)*K + k0, &lds[plane][half*64 + c*8][0]);
    }
    __syncthreads();
#pragma unroll
    for(int ks=0; ks<2; ++ks){
      bf16x8 af[4], bf[4];
#pragma unroll
      for(int mf=0; mf<4; ++mf)
        af[mf] = *(const bf16x8*)&lds[0][wm*64 + mf*16 + r15][(ks*4+g)*8];
#pragma unroll
      for(int nf=0; nf<4; ++nf)
        bf[nf] = *(const bf16x8*)&lds[1][wn*64 + nf*16 + r15][(ks*4+g)*8];
#pragma unroll
      for(int mf=0; mf<4; ++mf)
#pragma unroll
        for(int nf=0; nf<4; ++nf)
          acc[mf][nf] = __builtin_amdgcn_mfma_f32_16x16x32_bf16(af[mf], bf[nf], acc[mf][nf], 0,0,0);
    }
  }
#pragma unroll
  for(int mf=0; mf<4; ++mf){
#pragma unroll
    for(int nf=0; nf<4; ++nf){
      int col = col0 + wn*64 + nf*16 + r15;
      float bv = bias[col];
#pragma unroll
      for(int v=0; v<4; ++v){
        int row = row0 + wm*64 + mf*16 + g*4 + v;
        size_t o = (size_t)row*N + col;
        float val = acc[mf][nf][v] + bv;
        if (EPI == G2_GELU){ outh[o] = f2bf(gelu_exact(val)); }
        else {
          float gv = gate ? gate[(size_t)row*gstride] : 1.f;
          out[o] += gv * val;
        }
      }
    }
  }
}

// ---------------- pure-bf16 64x64-tile ACC GEMM (MoE GEMM2): grid (N/64, M/64) ---
__global__ __launch_bounds__(256,6) void gemm_acc64(
    const unsigned short* __restrict__ Ah,
    const unsigned short* __restrict__ Bh,
    const float* __restrict__ bias,
    float* __restrict__ out,
    int M, int K, int N,
    const float* __restrict__ gate, int gstride)
{
  __shared__ unsigned short lds[2][64][64];    // 16 KB
  int tid = threadIdx.x;
  int lane = tid & 63, w = tid >> 6;
  int wm = w >> 1, wn = w & 1;
  int nbx = gridDim.x;
  int nwg = nbx * gridDim.y;
  int orig = blockIdx.y*nbx + blockIdx.x;
  int cpx = nwg >> 3;
  int swz = (orig & 7)*cpx + (orig >> 3);
  int bx = swz % nbx, by = swz / nbx;
  int row0 = by*64, col0 = bx*64;
  int r15 = lane & 15, g = lane >> 4;
  int plane = w >> 1, half = w & 1;            // wave stages 32 rows of one plane
  const unsigned short* Pb = (plane==0) ? (Ah + (size_t)(row0+half*32)*K)
                                        : (Bh + (size_t)(col0+half*32)*K);
  const unsigned short* Pl = Pb + (size_t)(lane>>3)*K + (lane&7)*8;

  f32x4 acc[2][2];
#pragma unroll
  for(int i=0;i<2;++i)
#pragma unroll
    for(int j=0;j<2;++j) acc[i][j] = (f32x4){0.f,0.f,0.f,0.f};

  for(int k0=0; k0<K; k0+=64){
    __syncthreads();
#pragma unroll
    for(int c=0;c<4;++c){
      gload16(Pl + (size_t)(c*8)*K + k0, &lds[plane][half*32 + c*8][0]);
    }
    __syncthreads();
#pragma unroll
    for(int ks=0; ks<2; ++ks){
      bf16x8 af[2], bf[2];
#pragma unroll
      for(int mf=0; mf<2; ++mf)
        af[mf] = *(const bf16x8*)&lds[0][wm*32 + mf*16 + r15][(ks*4+g)*8];
#pragma unroll
      for(int nf=0; nf<2; ++nf)
        bf[nf] = *(const bf16x8*)&lds[1][wn*32 + nf*16 + r15][(ks*4+g)*8];
#pragma unroll
      for(int mf=0; mf<2; ++mf)
#pragma unroll
        for(int nf=0; nf<2; ++nf)
          acc[mf][nf] = __builtin_amdgcn_mfma_f32_16x16x32_bf16(af[mf], bf[nf], acc[mf][nf], 0,0,0);
    }
  }
#pragma unroll
  for(int mf=0; mf<2; ++mf){
#pragma unroll
    for(int nf=0; nf<2; ++nf){
      int col = col0 + wn*32 + nf*16 + r15;
      float bv = bias[col];
#pragma unroll
      for(int v=0; v<4; ++v){
        int row = row0 + wm*32 + mf*16 + g*4 + v;
        size_t o = (size_t)row*N + col;
        float gv = gate ? gate[(size_t)row*gstride] : 1.f;
        out[o] += gv * (acc[mf][nf][v] + bv);
      }
    }
  }
}

// ---------------- dedicated tiny GEMM: kvp = xp(32x512) @ kv_w(512x1024) + b -----
__global__ __launch_bounds__(256) void kvp_small_kernel(
    const float* __restrict__ xp, const float* __restrict__ W,
    const float* __restrict__ bias, float* __restrict__ out)
{
  __shared__ float xr[512];
  int row = blockIdx.y;            // 0..31
  int col = blockIdx.x*256 + threadIdx.x;
  float2 v = *(const float2*)(xp + (size_t)row*512 + threadIdx.x*2);
  xr[threadIdx.x*2]   = v.x;
  xr[threadIdx.x*2+1] = v.y;
  __syncthreads();
  float acc = 0.f;
#pragma unroll 8
  for(int k=0;k<512;++k)
    acc = fmaf(xr[k], W[(size_t)k*1024 + col], acc);
  out[(size_t)row*1024 + col] = acc + bias[col];
}

// ---------------- LayerNorm -> split bf16 planes ---------------------------------
__global__ __launch_bounds__(256) void ln_split_kernel(const float* __restrict__ in,
    const float* __restrict__ g, const float* __restrict__ b,
    unsigned short* __restrict__ outh, unsigned short* __restrict__ outl, float eps)
{
  int r = blockIdx.x;
  int tid = threadIdx.x;
  const float* rp = in + (size_t)r * D_;
  float2 v = *(const float2*)(rp + tid*2);
  float s = v.x + v.y;
  float q = v.x*v.x + v.y*v.y;
  s = wave_sum(s); q = wave_sum(q);
  __shared__ float ss[4], qq[4];
  int wid = tid >> 6, lane = tid & 63;
  if(lane==0){ ss[wid]=s; qq[wid]=q; }
  __syncthreads();
  float S = ss[0]+ss[1]+ss[2]+ss[3];
  float Q = qq[0]+qq[1]+qq[2]+qq[3];
  float mean = S * (1.f/D_);
  float var = Q * (1.f/D_) - mean*mean;
  float rstd = rsqrtf(var + eps);
  int d = tid*2;
  float o0 = (v.x-mean)*rstd*g[d]   + b[d];
  float o1 = (v.y-mean)*rstd*g[d+1] + b[d+1];
  unsigned short h0,l0,h1,l1;
  split2(o0,h0,l0); split2(o1,h1,l1);
  *(ushort2*)(outh + (size_t)r*D_ + d) = make_ushort2(h0,h1);
  *(ushort2*)(outl + (size_t)r*D_ + d) = make_ushort2(l0,l1);
}

// ---------------- q post (f32, in place) -----------------------------------------
__global__ __launch_bounds__(256) void qs_post_kernel(float* __restrict__ q,
                                                      const float* __restrict__ temp)
{
  int tid = threadIdx.x;
  int gid = blockIdx.x*4 + (tid>>6);
  int dd  = tid & 63;
  int h = gid % H_;
  int n = (gid / H_) % N_;
  int b = gid / (H_*N_);
  size_t idx = ((size_t)(b*N_+n))*D_ + h*HD_ + dd;
  float v = q[idx];
  float ss = wave_sum(v*v);
  v = v / fmaxf(sqrtf(ss), 1e-12f);
  float t = temp[h];
  float sp = log1pf(expf(t));
  v *= sp * 2.77258872223978124f;
  float partner = __shfl_xor(v, 32);
  int i = dd & 31;
  float inv = exp2f(-(float)i * LOG2_10000_OVER_32);
  float ang = (float)n * inv;
  float s, c; sincosf(ang, &s, &c);
  q[idx] = (dd < 32) ? fmaf(v, c, -partner*s) : fmaf(partner, s, v*c);
}

// ---------------- k post ---------------------------------------------------------
__global__ __launch_bounds__(256) void k_post_kernel(const float* __restrict__ kvb,
                                                     float* __restrict__ kln)
{
  int tid = threadIdx.x;
  int gid = blockIdx.x*4 + (tid>>6);
  int dd  = tid & 63;
  int h = gid % H_;
  int n = (gid / H_) % N_;
  int b = gid / (H_*N_);
  float v = kvb[((size_t)(b*N_+n))*(2*D_) + h*HD_ + dd];
  float partner = __shfl_xor(v, 32);
  int i = dd & 31;
  float inv = exp2f(-(float)i * LOG2_10000_OVER_32);
  float ang = (float)n * inv;
  float s, c; sincosf(ang, &s, &c);
  float r = (dd < 32) ? fmaf(v, c, -partner*s) : fmaf(partner, s, v*c);
  float ss = wave_sum(r*r);
  r = r / fmaxf(sqrtf(ss), 1e-12f);
  kln[((size_t)(b*N_+n))*D_ + h*HD_ + dd] = r;
}

// ---------------- pooled path ----------------------------------------------------
__global__ __launch_bounds__(256) void pool_ln_kernel(const float* __restrict__ src,
    const float* __restrict__ g, const float* __restrict__ b, float* __restrict__ xp)
{
  int bp = blockIdx.x;
  int bb = bp / P_, p = bp % P_;
  int tid = threadIdx.x;
  const float* base = src + ((size_t)(bb*N_ + p*(N_/P_)))*D_;
  float a0=0.f, a1=0.f;
  for(int i=0;i<N_/P_;++i){
    a0 += base[(size_t)i*D_ + tid];
    a1 += base[(size_t)i*D_ + tid + 256];
  }
  a0 *= (1.f/(N_/P_)); a1 *= (1.f/(N_/P_));
  float s = a0+a1, q = a0*a0+a1*a1;
  s = wave_sum(s); q = wave_sum(q);
  __shared__ float ss[4], qq[4];
  int wid = tid>>6, lane = tid&63;
  if(lane==0){ ss[wid]=s; qq[wid]=q; }
  __syncthreads();
  float S = ss[0]+ss[1]+ss[2]+ss[3];
  float Q = qq[0]+qq[1]+qq[2]+qq[3];
  float mean = S*(1.f/D_);
  float var  = Q*(1.f/D_) - mean*mean;
  float rstd = rsqrtf(var + 1e-5f);
  xp[(size_t)bp*D_ + tid]       = (a0-mean)*rstd*g[tid]     + b[tid];
  xp[(size_t)bp*D_ + tid + 256] = (a1-mean)*rstd*g[tid+256] + b[tid+256];
}

// ---------------- kP rope --------------------------------------------------------
__global__ __launch_bounds__(512) void kp_rope_kernel(const float* __restrict__ kvp,
                                                      float* __restrict__ kpb)
{
  int bp = blockIdx.x;
  int d  = threadIdx.x;
  int dd = d & 63;
  int p  = bp % P_;
  float v = kvp[(size_t)bp*(2*D_) + d];
  float partner = __shfl_xor(v, 32);
  int i = dd & 31;
  float inv = exp2f(-(float)i * LOG2_10000_OVER_32);
  float ang = (float)p * inv;
  float s, c; sincosf(ang, &s, &c);
  kpb[(size_t)bp*D_ + d] = (dd < 32) ? fmaf(v, c, -partner*s) : fmaf(partner, s, v*c);
}

// ---------------- attention: 8-lane groups ---------------------------------------
static __device__ __forceinline__ float dot4(float4 a, float4 b){
  return fmaf(a.x,b.x, fmaf(a.y,b.y, fmaf(a.z,b.z, a.w*b.w)));
}

__global__ __launch_bounds__(256) void attn_kernel(
    const float* __restrict__ qs, const float* __restrict__ kln,
    const float* __restrict__ kvb, const float* __restrict__ kpb,
    const float* __restrict__ kvp,
    unsigned short* __restrict__ outh, unsigned short* __restrict__ outl)
{
  int tid = threadIdx.x;
  int gid = blockIdx.x*32 + (tid>>3);  // (b*N+n)*H + h
  int l   = tid & 7;
  int d0  = l*8;
  int h = gid % H_;
  int n = (gid / H_) % N_;
  int b = gid / (H_*N_);
  size_t tok = (size_t)(b*N_+n);
  const float* qp = qs + tok*D_ + h*HD_ + d0;
  float4 qa = *(const float4*)qp;
  float4 qb = *(const float4*)(qp+4);
  float lg[KW_+P_];
#pragma unroll
  for(int j=0;j<KW_;++j){
    int np  = n - KW_/2 + j;
    int npc = min(max(np,0), N_-1);
    const float* kp = kln + ((size_t)(b*N_+npc))*D_ + h*HD_ + d0;
    float4 ka = *(const float4*)kp;
    float4 kb = *(const float4*)(kp+4);
    float d = dot4(qa,ka) + dot4(qb,kb);
#pragma unroll
    for(int off=1; off<8; off<<=1) d += __shfl_xor(d, off);
    lg[j] = (np>=0 && np<N_) ? d : -3.0e38f;
  }
#pragma unroll
  for(int p=0;p<P_;++p){
    const float* kp = kpb + ((size_t)(b*P_+p))*D_ + h*HD_ + d0;
    float4 ka = *(const float4*)kp;
    float4 kb = *(const float4*)(kp+4);
    float d = dot4(qa,ka) + dot4(qb,kb);
#pragma unroll
    for(int off=1; off<8; off<<=1) d += __shfl_xor(d, off);
    lg[KW_+p] = d;
  }
  float m = lg[0];
#pragma unroll
  for(int j=1;j<KW_+P_;++j) m = fmaxf(m, lg[j]);
  float a[KW_+P_]; float sum = 0.f;
#pragma unroll
  for(int j=0;j<KW_+P_;++j){ a[j] = expf(lg[j]-m); sum += a[j]; }
  float inv = 1.f / sum;
  float4 oa = make_float4(0.f,0.f,0.f,0.f);
  float4 ob = make_float4(0.f,0.f,0.f,0.f);
#pragma unroll
  for(int j=0;j<KW_;++j){
    int npc = min(max(n - KW_/2 + j, 0), N_-1);
    const float* vp = kvb + ((size_t)(b*N_+npc))*(2*D_) + D_ + h*HD_ + d0;
    float4 va = *(const float4*)vp;
    float4 vb = *(const float4*)(vp+4);
    oa.x=fmaf(a[j],va.x,oa.x); oa.y=fmaf(a[j],va.y,oa.y); oa.z=fmaf(a[j],va.z,oa.z); oa.w=fmaf(a[j],va.w,oa.w);
    ob.x=fmaf(a[j],vb.x,ob.x); ob.y=fmaf(a[j],vb.y,ob.y); ob.z=fmaf(a[j],vb.z,ob.z); ob.w=fmaf(a[j],vb.w,ob.w);
  }
#pragma unroll
  for(int p=0;p<P_;++p){
    float w = a[KW_+p];
    const float* vp = kvp + ((size_t)(b*P_+p))*(2*D_) + D_ + h*HD_ + d0;
    float4 va = *(const float4*)vp;
    float4 vb = *(const float4*)(vp+4);
    oa.x=fmaf(w,va.x,oa.x); oa.y=fmaf(w,va.y,oa.y); oa.z=fmaf(w,va.z,oa.z); oa.w=fmaf(w,va.w,oa.w);
    ob.x=fmaf(w,vb.x,ob.x); ob.y=fmaf(w,vb.y,ob.y); ob.z=fmaf(w,vb.z,ob.z); ob.w=fmaf(w,vb.w,ob.w);
  }
  unsigned short h0,h1,h2,h3,l0,l1,l2,l3;
  size_t ob_ = tok*D_ + h*HD_ + d0;
  split2(oa.x*inv,h0,l0); split2(oa.y*inv,h1,l1); split2(oa.z*inv,h2,l2); split2(oa.w*inv,h3,l3);
  *(ushort4*)(outh + ob_)   = make_ushort4(h0,h1,h2,h3);
  *(ushort4*)(outl + ob_)   = make_ushort4(l0,l1,l2,l3);
  split2(ob.x*inv,h0,l0); split2(ob.y*inv,h1,l1); split2(ob.z*inv,h2,l2); split2(ob.w*inv,h3,l3);
  *(ushort4*)(outh + ob_+4) = make_ushort4(h0,h1,h2,h3);
  *(ushort4*)(outl + ob_+4) = make_ushort4(l0,l1,l2,l3);
}

// ---------------- router + stats (reads split xn2) -------------------------------
__global__ void zero_stats_kernel(float* stats){
  if(threadIdx.x < 16) stats[threadIdx.x] = 0.f;
}

__global__ __launch_bounds__(256) void router_kernel(
    const unsigned short* __restrict__ xh, const unsigned short* __restrict__ xl,
    const float* __restrict__ rw, const float* __restrict__ rb,
    float* __restrict__ gates, float* __restrict__ stats)
{
  int tid = threadIdx.x;
  int wid = tid>>6, lane = tid&63;
  int t = blockIdx.x*4 + wid;
  float a0=0.f,a1=0.f,a2=0.f,a3=0.f;
  for(int k=lane;k<D_;k+=64){
    float xv = bf2f(xh[(size_t)t*D_+k]) + bf2f(xl[(size_t)t*D_+k]);
    float4 w = *(const float4*)(rw + (size_t)k*E_);
    a0 = fmaf(xv,w.x,a0); a1 = fmaf(xv,w.y,a1);
    a2 = fmaf(xv,w.z,a2); a3 = fmaf(xv,w.w,a3);
  }
  a0=wave_sum(a0); a1=wave_sum(a1); a2=wave_sum(a2); a3=wave_sum(a3);
  __shared__ float sg[4][E_], sc[4][E_];
  if(lane==0){
    float lg[E_] = {a0+rb[0], a1+rb[1], a2+rb[2], a3+rb[3]};
    float m = fmaxf(fmaxf(lg[0],lg[1]), fmaxf(lg[2],lg[3]));
    float e[E_]; float sum=0.f;
#pragma unroll
    for(int k=0;k<E_;++k){ e[k]=expf(lg[k]-m); sum+=e[k]; }
    float inv = 1.f/sum;
    int am = 0; float bv = lg[0];
#pragma unroll
    for(int k=1;k<E_;++k) if(lg[k] > bv){ bv = lg[k]; am = k; }
#pragma unroll
    for(int k=0;k<E_;++k){
      float gk = e[k]*inv;
      gates[(size_t)t*E_ + k] = gk;
      sg[wid][k] = gk;
      sc[wid][k] = (k==am) ? 1.f : 0.f;
    }
  }
  __syncthreads();
  if(tid < E_){
    atomicAdd(stats + tid,      sc[0][tid]+sc[1][tid]+sc[2][tid]+sc[3][tid]);
    atomicAdd(stats + E_ + tid, sg[0][tid]+sg[1][tid]+sg[2][tid]+sg[3][tid]);
  }
}

__global__ void aux_kernel(const float* __restrict__ stats, float* __restrict__ outp){
  float acc = 0.f;
  const float inv = 1.f / (float)TOK_;
#pragma unroll
  for(int e=0;e<E_;++e) acc += (stats[e]*inv) * (stats[E_+e]*inv);
  *outp = 0.01f * (float)E_ * acc;
}

// =================================================================================
extern "C" void kernel_launch(void* const* d_in, const int* in_sizes, int n_in,
                              void* d_out, int out_size, void* d_ws, size_t ws_size,
                              hipStream_t stream)
{
  const float* x      = (const float*)d_in[0];
  const float* temp   = (const float*)d_in[1];
  const float* q_w    = (const float*)d_in[2];
  const float* q_b    = (const float*)d_in[3];
  const float* kv_w   = (const float*)d_in[4];
  const float* kv_b   = (const float*)d_in[5];
  const float* proj_w = (const float*)d_in[6];
  const float* proj_b = (const float*)d_in[7];
  const float* n1g    = (const float*)d_in[8];
  const float* n1b    = (const float*)d_in[9];
  const float* n2g    = (const float*)d_in[10];
  const float* n2b    = (const float*)d_in[11];
  const float* sr_w   = (const float*)d_in[12];
  const float* sr_b   = (const float*)d_in[13];
  const float* npg    = (const float*)d_in[14];
  const float* npb    = (const float*)d_in[15];
  const float* rw     = (const float*)d_in[16];
  const float* rb     = (const float*)d_in[17];
  const float* ew1    = (const float*)d_in[18];
  const float* eb1    = (const float*)d_in[19];
  const float* ew2    = (const float*)d_in[20];
  const float* eb2    = (const float*)d_in[21];
  const float* sw1    = (const float*)d_in[22];
  const float* sb1    = (const float*)d_in[23];
  const float* sw2    = (const float*)d_in[24];
  const float* sb2    = (const float*)d_in[25];

  float* out = (float*)d_out;
  const size_t S = (size_t)TOK_ * D_;          // 4,194,304
  char* base = (char*)d_ws;
  size_t off = 0;
  auto aus = [&](size_t n)->unsigned short*{ unsigned short* p=(unsigned short*)(base+off); off += n*2; return p; };
  auto af  = [&](size_t n)->float*{ float* p=(float*)(base+off); off += n*4; return p; };

  // persistent weight planes (transposed [N][K]); fwh/fwl = fused [q|kv|sr] N=2048
  unsigned short *fwh = aus((size_t)2048*512), *fwl = aus((size_t)2048*512);
  unsigned short *pjwh= aus(512*512),  *pjwl= aus(512*512);
  unsigned short *s1h = aus(512*2048), *s1l = aus(512*2048);
  unsigned short *s2h = aus(2048*512), *s2l = aus(2048*512);
  unsigned short *e1h = aus((size_t)E_*512*2048), *e1l = aus((size_t)E_*512*2048);
  unsigned short *e2h = aus((size_t)E_*2048*512), *e2l = aus((size_t)E_*2048*512);
  // xn planes (reused later as xn2 planes)
  unsigned short *xnh = aus(S), *xnl = aus(S);
  // f32 region: qsb + kvb + kln (reused later as hid bf16 plane, 4S elems)
  float* qsb = af(S);
  float* kvb = af(2*S);
  float* kln = af(S);
  unsigned short* hidh = (unsigned short*)qsb;   // 4S ushorts fit in qsb+kvb
  // srg f32 (reused later as attn_out planes)
  float* srg = af(S);
  unsigned short* atth = (unsigned short*)srg;
  unsigned short* attl = atth + S;
  // small tail
  float* xp    = af((size_t)B_*P_*D_);
  float* kvp   = af((size_t)B_*P_*2*D_);
  float* kpb   = af((size_t)B_*P_*D_);
  float* gates = af((size_t)TOK_*E_);
  float* stats = af(16);

  // 0. weight convert+transpose+split (q|kv|sr packed into fused planes)
  wconv_kernel<<<dim3(8,8,1),  256, 0, stream>>>(q_w,  fwh,                 fwl,                 512, 512);
  wconv_kernel<<<dim3(16,8,1), 256, 0, stream>>>(kv_w, fwh+(size_t)512*512, fwl+(size_t)512*512, 512, 1024);
  wconv_kernel<<<dim3(8,8,1),  256, 0, stream>>>(sr_w, fwh+(size_t)1536*512,fwl+(size_t)1536*512,512, 512);
  wconv_kernel<<<dim3(8,8,1),  256, 0, stream>>>(proj_w, pjwh,pjwl, 512, 512);
  wconv_kernel<<<dim3(32,8,1), 256, 0, stream>>>(sw1,    s1h, s1l,  512, 2048);
  wconv_kernel<<<dim3(8,32,1), 256, 0, stream>>>(sw2,    s2h, s2l,  2048,512);
  wconv_kernel<<<dim3(32,8,E_),256, 0, stream>>>(ew1,    e1h, e1l,  512, 2048);
  wconv_kernel<<<dim3(8,32,E_),256, 0, stream>>>(ew2,    e2h, e2l,  2048,512);

  // 1. xn = LN1(x) -> split planes
  ln_split_kernel<<<dim3(TOK_), 256, 0, stream>>>(x, n1g, n1b, xnh, xnl, 1e-6f);
  // 2-4. fused QKVSR GEMM: q->qsb, kv->kvb, gelu(sr)->srg  (grid 1024 = 4 blk/CU)
  gemm_qkvsr<<<dim3(16,64), 256, 0, stream>>>(xnh,xnl, fwh,fwl, q_b,kv_b,sr_b,
                                              qsb,kvb,srg, TOK_, 512);
  // 5. xp = LN(mean-pool)
  pool_ln_kernel<<<dim3(B_*P_), 256, 0, stream>>>(srg, npg, npb, xp);
  // 6. kvp = xp @ kv_w + kv_b (dedicated small-M kernel)
  kvp_small_kernel<<<dim3(4,32), 256, 0, stream>>>(xp, kv_w, kv_b, kvp);
  // 7. kP = rope(kvp[:, :D])
  kp_rope_kernel<<<dim3(B_*P_), 512, 0, stream>>>(kvp, kpb);
  // 8. qs post
  qs_post_kernel<<<dim3(B_*N_*H_/4), 256, 0, stream>>>(qsb, temp);
  // 9. kln
  k_post_kernel<<<dim3(B_*N_*H_/4), 256, 0, stream>>>(kvb, kln);
  // 10. attention -> split attn_out (8-lane groups)
  attn_kernel<<<dim3(B_*H_*N_/32), 256, 0, stream>>>(qsb, kln, kvb, kpb, kvp, atth, attl);
  // 11. out = x + attn_out @ proj_w + proj_b
  gemm_mfma<GEPI_RESID><<<dim3(4,64), 256, 0, stream>>>(atth,attl,pjwh,pjwl,proj_b, out, TOK_,512,512, x);
  // 12. xn2 = LN2(out) -> split planes (reuse xn region)
  ln_split_kernel<<<dim3(TOK_), 256, 0, stream>>>(out, n2g, n2b, xnh, xnl, 1e-6f);
  // 13-14. router + stats
  zero_stats_kernel<<<dim3(1), 64, 0, stream>>>(stats);
  router_kernel<<<dim3(TOK_/4), 256, 0, stream>>>(xnh, xnl, rw, rb, gates, stats);
  // 15. MoE: GEMM1 = 128^2 bf16 (1024 blocks); GEMM2 = 64^2 bf16 ACC (1024 blocks)
  gemm_bf16<G2_GELU><<<dim3(16,64), 256, 0, stream>>>(xnh, s1h, sb1, nullptr, hidh, TOK_,512,HID_, nullptr,0);
  gemm_acc64<<<dim3(8,128), 256, 0, stream>>>(hidh, s2h, sb2, out, TOK_,HID_,512, nullptr,0);
  for(int e=0;e<E_;++e){
    gemm_bf16<G2_GELU><<<dim3(16,64), 256, 0, stream>>>(xnh, e1h+(size_t)e*512*2048, eb1+(size_t)e*HID_, nullptr, hidh, TOK_,512,HID_, nullptr,0);
    gemm_acc64<<<dim3(8,128), 256, 0, stream>>>(hidh, e2h+(size_t)e*2048*512, eb2+(size_t)e*D_, out, TOK_,HID_,512, gates+e,E_);
  }
  // 16. aux scalar
  aux_kernel<<<dim3(1), 1, 0, stream>>>(stats, out + S);
}